// Round 1
// baseline (393.457 us; speedup 1.0000x reference)
//
#include <hip/hip_runtime.h>
#include <hip/hip_bf16.h>

// Problem constants
#define NB 16
#define SS 7500
#define HH 64
#define TT 300
#define NHEAD 4
#define DKV 64
#define NJ 25
#define HDW 256
#define NQT 19
#define NST 10       // s-tiles of 32

typedef __attribute__((ext_vector_type(8))) short short8;
typedef __attribute__((ext_vector_type(4))) short s16x4;
typedef __attribute__((ext_vector_type(4))) float f32x4;

__device__ inline short f2bf(float f) {
    union { float f; unsigned u; } x; x.f = f;
    unsigned u = x.u + 0x7FFFu + ((x.u >> 16) & 1u);
    return (short)(u >> 16);
}
__device__ inline unsigned pk2(float a, float b) {  // packed fp32x2 -> bf16x2
    __hip_bfloat162 h = __float22bfloat162_rn(make_float2(a, b));
    union { __hip_bfloat162 h; unsigned u; } c; c.h = h; return c.u;
}
#define MFMA32(a, b, c) __builtin_amdgcn_mfma_f32_16x16x32_bf16((a), (b), (c), 0, 0, 0)
#define LGKM_BAR() asm volatile("s_waitcnt lgkmcnt(0)" ::: "memory")

// 16x16x16 bf16 MFMA: operand k-granularity quad*4+i == C-frag row granularity,
// so all P/Q'/O relayouts are in-lane packs (no LDS scratch, no shuffles).
__device__ __forceinline__ f32x4 MFMA16(s16x4 a, s16x4 b, f32x4 c) {
#if __has_builtin(__builtin_amdgcn_mfma_f32_16x16x16bf16_1k)
    return __builtin_amdgcn_mfma_f32_16x16x16bf16_1k(a, b, c, 0, 0, 0);
#else
    // zero-padded K=32 fallback: A/B k-slots line up, upper half contributes 0
    short8 a8 = {a[0], a[1], a[2], a[3], 0, 0, 0, 0};
    short8 b8 = {b[0], b[1], b[2], b[3], 0, 0, 0, 0};
    return MFMA32(a8, b8, c);
#endif
}

__device__ __forceinline__ s16x4 lo4(short8 x) { return __builtin_shufflevector(x, x, 0, 1, 2, 3); }
__device__ __forceinline__ s16x4 hi4(short8 x) { return __builtin_shufflevector(x, x, 4, 5, 6, 7); }
__device__ __forceinline__ s16x4 pks4(unsigned a, unsigned b) {
    union { uint2 u; s16x4 s; } c; c.u.x = a; c.u.y = b; return c.s;
}
__device__ __forceinline__ short8 packx(const float* px) {
    const float4 x0 = *(const float4*)px;
    const float4 x1 = *(const float4*)(px + 4);
    union { uint4 u; short8 s; } cv;
    cv.u.x = pk2(x0.x, x0.y); cv.u.y = pk2(x0.z, x0.w);
    cv.u.z = pk2(x1.x, x1.y); cv.u.w = pk2(x1.z, x1.w);
    return cv.s;
}

// ws layout (bf16 units): QKV B-frags (96 frags x 512 shorts) + Wo K=16 frags
// (64 frags x 256 shorts). 131072 bytes total.
#define WS_BYTES ((size_t)65536 * 2)
#define WOBASE 49152

// ---------------- A0: weights -> bf16 fragment arrays ----------------
// f<96: {Wq,Wk,Wv}[matid=f/32], nt=(f%32)/2, kt=f%2; 16x16x32 frag, ld=256,K=64.
//       (A-frag and B-frag lane maps are identical, so these serve both roles.)
// f>=96: Wo K=16 frags, g=f-96: nt=g&3 (out-col tile), kt=g>>2 (K-chunk of 16).
__global__ void wfrag_kernel(const float* __restrict__ Wq, const float* __restrict__ Wk,
                             const float* __restrict__ Wv, const float* __restrict__ Wo,
                             unsigned short* __restrict__ ws) {
    const int f = blockIdx.x;
    const int lane = threadIdx.x;
    const int L15 = lane & 15, quad = lane >> 4;
    if (f < 96) {
        const int matid = f >> 5, nt = (f & 31) >> 1, kt = f & 1;
        const float* W = matid == 0 ? Wq : (matid == 1 ? Wk : Wv);
        const int n = nt * 16 + L15;
        unsigned short* dst = ws + f * 512 + lane * 8;
        #pragma unroll
        for (int i = 0; i < 8; ++i)
            dst[i] = (unsigned short)f2bf(W[(kt * 32 + quad * 8 + i) * HDW + n]);
    } else {
        const int g = f - 96, nt = g & 3, kt = g >> 2;
        const int n = nt * 16 + L15;
        unsigned short* dst = ws + WOBASE + g * 256 + lane * 4;
        #pragma unroll
        for (int i = 0; i < 4; ++i)
            dst[i] = (unsigned short)f2bf(Wo[(kt * 16 + quad * 4 + i) * HH + n]);
    }
}

// ---------------- fully fused: proj + attention + out-proj ----------------
// 512 threads (8 waves), LDS 79.4KB, VGPR<=128 => 2 blocks/CU (16 waves/CU).
// sK[row 0..299][64]: K'^T rows; 16-short blocks XOR-swizzled by (row&3).
//   paired k-chunks: shorts [p*32+quad*8 .. +7] = frags kc=2p (lo4) / 2p+1 (hi4).
// sV[d 0..63][320]: V'^T; blocks (st*2 + quad>>1) XOR (d&3); shorts
//   [st*32+quad*8 .. +7] = rh0 (lo4) / rh1 (hi4) k-chunks.
// Both read (b128) and write (b64) patterns are at the structural bank minimum.

__device__ __forceinline__ void qproj(const float* __restrict__ qg, long xbase,
                                      const unsigned short* __restrict__ wf,
                                      int h, int t, int L15, int quad, int lane,
                                      s16x4* qa) {
    int r = t * 16 + L15; if (r > TT - 1) r = TT - 1;
    const float* px = qg + xbase + (long)r * HH + quad * 8;
    const short8 xf0 = packx(px);
    const short8 xf1 = packx(px + 32);
    #pragma unroll
    for (int ntl = 0; ntl < 4; ++ntl) {
        const short8 b0 = *(const short8*)&wf[((h * 4 + ntl) * 2 + 0) * 512 + lane * 8];
        const short8 b1 = *(const short8*)&wf[((h * 4 + ntl) * 2 + 1) * 512 + lane * 8];
        f32x4 c = {0.f, 0.f, 0.f, 0.f};
        c = MFMA32(b0, xf0, c);   // A=W (swapped) => C = Q'^T[d'][q], q on L15
        c = MFMA32(b1, xf1, c);
        // in-lane pack to B-frag for K=16 QK (scale 1/8 folded)
        qa[ntl] = pks4(pk2(c[0] * 0.125f, c[1] * 0.125f),
                       pk2(c[2] * 0.125f, c[3] * 0.125f));
    }
}

template <int NSUB>
__device__ __forceinline__ void attn_pass(const unsigned short* __restrict__ sK,
                                          const unsigned short* __restrict__ sV,
                                          const s16x4 qa[][4], f32x4 oT[][4],
                                          float* __restrict__ lsum,
                                          int L15, int quad) {
    for (int st = 0; st < NST; ++st) {
        s16x4 pt[NSUB][2];
        #pragma unroll
        for (int rh = 0; rh < 2; ++rh) {
            int row = st * 32 + rh * 16 + L15; if (row > TT - 1) row = TT - 1;
            const int rb = row * 64 + ((quad & 1) << 3);
            const short8 k0 = *(const short8*)&sK[rb + ((((quad >> 1) | 0) ^ (row & 3)) << 4)];
            const short8 k1 = *(const short8*)&sK[rb + ((((quad >> 1) | 2) ^ (row & 3)) << 4)];
            #pragma unroll
            for (int su = 0; su < NSUB; ++su) {
                f32x4 c = {0.f, 0.f, 0.f, 0.f};
                c = MFMA16(lo4(k0), qa[su][0], c);
                c = MFMA16(hi4(k0), qa[su][1], c);
                c = MFMA16(lo4(k1), qa[su][2], c);
                c = MFMA16(hi4(k1), qa[su][3], c);
                if (st == NST - 1) {      // mask s >= 300
                    if (rh == 1 || quad == 3) {
                        c[0] = -1e38f; c[1] = -1e38f; c[2] = -1e38f; c[3] = -1e38f;
                    }
                }
                // fixed-max softmax p=exp(s-16); exact after 1/l
                const float p0 = __expf(c[0] - 16.f);
                const float p1 = __expf(c[1] - 16.f);
                const float p2 = __expf(c[2] - 16.f);
                const float p3 = __expf(c[3] - 16.f);
                lsum[su] += (p0 + p1) + (p2 + p3);
                pt[su][rh] = pks4(pk2(p0, p1), pk2(p2, p3));   // in-lane B-frag
            }
        }
        #pragma unroll
        for (int nt = 0; nt < 4; ++nt) {
            const int d = nt * 16 + L15;
            const int blk = ((st << 1) | (quad >> 1)) ^ (d & 3);
            const short8 vp = *(const short8*)&sV[d * 320 + (blk << 4) + ((quad & 1) << 3)];
            #pragma unroll
            for (int su = 0; su < NSUB; ++su) {
                oT[su][nt] = MFMA16(lo4(vp), pt[su][0], oT[su][nt]);
                oT[su][nt] = MFMA16(hi4(vp), pt[su][1], oT[su][nt]);
            }
        }
    }
}

__device__ __forceinline__ void epilogue(const unsigned short* __restrict__ wf, int h,
                                         float lsum, const f32x4* oT, f32x4* y, int lane) {
    lsum += __shfl_xor(lsum, 16);
    lsum += __shfl_xor(lsum, 32);
    const float linv = 1.f / lsum;
    s16x4 oa[4];
    #pragma unroll
    for (int nt = 0; nt < 4; ++nt)     // in-lane A-frag pack (K=16 chunks of d)
        oa[nt] = pks4(pk2(oT[nt][0] * linv, oT[nt][1] * linv),
                      pk2(oT[nt][2] * linv, oT[nt][3] * linv));
    #pragma unroll
    for (int nc = 0; nc < 4; ++nc) {
        #pragma unroll
        for (int kc = 0; kc < 4; ++kc) {
            const s16x4 wb = *(const s16x4*)&wf[WOBASE + (((h * 4 + kc) * 4 + nc) << 8) + (lane << 2)];
            y[nc] = MFMA16(oa[kc], wb, y[nc]);
        }
    }
}

__device__ __forceinline__ void store_tile(float* __restrict__ out, long xbase, int tile,
                                           const f32x4* y, int L15, int quad) {
    #pragma unroll
    for (int nc = 0; nc < 4; ++nc)
        #pragma unroll
        for (int rr = 0; rr < 4; ++rr) {
            const int row = tile * 16 + quad * 4 + rr;
            if (row < TT)
                out[xbase + (long)row * HH + nc * 16 + L15] = y[nc][rr];
        }
}

__global__ __launch_bounds__(512, 4)
void attn4(const float* __restrict__ q, const float* __restrict__ k,
           const float* __restrict__ v, const unsigned short* __restrict__ wf,
           float* __restrict__ out)
{
    __shared__ __align__(16) unsigned short sK[19200];   // 38400 B
    __shared__ __align__(16) unsigned short sV[20480];   // 40960 B

    const int tid = threadIdx.x;
    const int w = tid >> 6, lane = tid & 63;
    const int L15 = lane & 15, quad = lane >> 4;
    const int bj = blockIdx.x;
    const int b = bj / NJ, j = bj % NJ;
    const long xbase = ((long)b * SS + (long)j * TT) * HH;

    // zero V pad (logical s 288..319 of st=9; valid parts rewritten each head)
    for (int i = tid; i < 2048; i += 512) {
        const int d = i >> 5, off = 288 + (i & 31);
        const int blk = (off >> 4) ^ (d & 3);
        sV[d * 320 + (blk << 4) + (off & 15)] = 0;
    }

    f32x4 y[3][4];
    #pragma unroll
    for (int sl = 0; sl < 3; ++sl)
        #pragma unroll
        for (int n = 0; n < 4; ++n) { y[sl][n][0]=0.f; y[sl][n][1]=0.f; y[sl][n][2]=0.f; y[sl][n][3]=0.f; }

    for (int h = 0; h < NHEAD; ++h) {
        __syncthreads();   // prior head's sK/sV readers done (also orders init)

        // ---- K'/V' projection into LDS: 38 jobs of 16 rows over 8 waves ----
        for (int jb = w; jb < 38; jb += 8) {
            const int isV = jb >= 19;
            const int t = isV ? jb - 19 : jb;
            const float* X = isV ? v : k;
            const unsigned short* mb = wf + (isV ? 2 : 1) * 16384;
            int r = t * 16 + L15; if (r > TT - 1) r = TT - 1;
            const float* px = X + xbase + (long)r * HH + quad * 8;
            const short8 xf0 = packx(px);
            const short8 xf1 = packx(px + 32);
            if (!isV) {
                const int s = t * 16 + L15;   // unclamped store row
                #pragma unroll
                for (int ntl = 0; ntl < 4; ++ntl) {
                    const short8 b0 = *(const short8*)&mb[((h * 4 + ntl) * 2 + 0) * 512 + lane * 8];
                    const short8 b1 = *(const short8*)&mb[((h * 4 + ntl) * 2 + 1) * 512 + lane * 8];
                    f32x4 c = {0.f, 0.f, 0.f, 0.f};
                    c = MFMA32(b0, xf0, c);   // A=W => C = K'^T[d'][s], s on L15
                    c = MFMA32(b1, xf1, c);
                    if (s < TT) {
                        uint2 pkd; pkd.x = pk2(c[0], c[1]); pkd.y = pk2(c[2], c[3]);
                        const int pp = ntl >> 1, oo = ntl & 1;
                        const int blk = ((pp << 1) | (quad >> 1)) ^ (s & 3);
                        *(uint2*)&sK[s * 64 + (blk << 4) + ((quad & 1) << 3) + (oo << 2)] = pkd;
                    }
                }
            } else {
                const int sb = t * 16 + quad * 4;
                const int stv = t >> 1, rhv = t & 1;
                #pragma unroll
                for (int ntl = 0; ntl < 4; ++ntl) {
                    const short8 b0 = *(const short8*)&mb[((h * 4 + ntl) * 2 + 0) * 512 + lane * 8];
                    const short8 b1 = *(const short8*)&mb[((h * 4 + ntl) * 2 + 1) * 512 + lane * 8];
                    f32x4 c = {0.f, 0.f, 0.f, 0.f};
                    c = MFMA32(xf0, b0, c);   // A=x => C = V'[s][d], d on L15
                    c = MFMA32(xf1, b1, c);
                    if (sb < TT) {
                        const int d = ntl * 16 + L15;
                        uint2 pkd; pkd.x = pk2(c[0], c[1]); pkd.y = pk2(c[2], c[3]);
                        const int blk = ((stv << 1) | (quad >> 1)) ^ (d & 3);
                        *(uint2*)&sV[d * 320 + (blk << 4) + ((quad & 1) << 3) + (rhv << 2)] = pkd;
                    }
                }
            }
        }

        // ---- Q' for pass-1 tiles (overlaps LDS write drain; no LDS used) ----
        s16x4 qa[2][4];
        qproj(q, xbase, wf, h, 2 * w + 0, L15, quad, lane, qa[0]);
        qproj(q, xbase, wf, h, 2 * w + 1, L15, quad, lane, qa[1]);

        __syncthreads();   // sK/sV complete

        // ---- pass 1: joint 2 q-tiles, barrier-free st loop ----
        f32x4 oT[2][4]; float ls[2] = {0.f, 0.f};
        #pragma unroll
        for (int su = 0; su < 2; ++su)
            #pragma unroll
            for (int n = 0; n < 4; ++n) { oT[su][n][0]=0.f; oT[su][n][1]=0.f; oT[su][n][2]=0.f; oT[su][n][3]=0.f; }
        attn_pass<2>(sK, sV, qa, oT, ls, L15, quad);
        epilogue(wf, h, ls[0], oT[0], y[0], lane);
        epilogue(wf, h, ls[1], oT[1], y[1], lane);

        // ---- pass 2: leftover tiles 16..18 on waves 5..7 ----
        if (w >= 5) {
            s16x4 qb[1][4];
            qproj(q, xbase, wf, h, 11 + w, L15, quad, lane, qb[0]);
            f32x4 o2[1][4]; float ls2[1] = {0.f};
            #pragma unroll
            for (int n = 0; n < 4; ++n) { o2[0][n][0]=0.f; o2[0][n][1]=0.f; o2[0][n][2]=0.f; o2[0][n][3]=0.f; }
            attn_pass<1>(sK, sV, qb, o2, ls2, L15, quad);
            epilogue(wf, h, ls2[0], o2[0], y[2], lane);
        }
    }

    store_tile(out, xbase, 2 * w + 0, y[0], L15, quad);
    store_tile(out, xbase, 2 * w + 1, y[1], L15, quad);
    if (w >= 5) store_tile(out, xbase, 11 + w, y[2], L15, quad);
}

// ================= Fallback (proven R2 kernel) for tiny ws =================
#define TPAD 320
#define KSTR 72
#define VSTR 328
#define WSTR 72
#define NWAVE 8
#define MAXTILE 3

__global__ __launch_bounds__(512, 1)
void mha_mfma(const float* __restrict__ q, const float* __restrict__ k,
              const float* __restrict__ v,
              const float* __restrict__ Wq, const float* __restrict__ Wk,
              const float* __restrict__ Wv, const float* __restrict__ Wo,
              float* __restrict__ out)
{
    __shared__ short sK [TPAD * KSTR];
    __shared__ short sVT[DKV * VSTR];
    __shared__ short sWq[DKV * WSTR];
    __shared__ short sWk[DKV * WSTR];
    __shared__ short sWv[DKV * WSTR];
    __shared__ short sWo[DKV * WSTR];
    __shared__ short sScrF[NWAVE][16 * KSTR];

    const int tid  = threadIdx.x;
    const int w    = tid >> 6;
    const int lane = tid & 63;
    const int L15  = lane & 15;
    const int quad = lane >> 4;

    const int blk = blockIdx.x;
    const int j = blk % NJ;
    const int b = blk / NJ;
    const long xbase = ((long)b * SS + (long)j * TT) * HH;

    for (int idx = tid; idx < 20 * KSTR; idx += 512) sK[300 * KSTR + idx] = 0;
    for (int idx = tid; idx < DKV * 32; idx += 512) {
        const int d = idx >> 5, c = 300 + (idx & 31);
        if (c < VSTR) sVT[d * VSTR + c] = 0;
    }

    int myT[MAXTILE]; int nMy = 0;
    for (int t = w; t < NQT; t += NWAVE) myT[nMy++] = t;

    f32x4 y[MAXTILE][4];
    #pragma unroll
    for (int a = 0; a < MAXTILE; ++a)
        #pragma unroll
        for (int n = 0; n < 4; ++n) { y[a][n][0]=0.f; y[a][n][1]=0.f; y[a][n][2]=0.f; y[a][n][3]=0.f; }

    for (int h = 0; h < NHEAD; ++h) {
        __syncthreads();
        for (int idx = tid; idx < 4096; idx += 512) {
            const int d = idx & 63;
            const int i = idx >> 6;
            sWq[d * WSTR + i] = f2bf(Wq[i * HDW + h * DKV + d]);
            sWk[d * WSTR + i] = f2bf(Wk[i * HDW + h * DKV + d]);
            sWv[d * WSTR + i] = f2bf(Wv[i * HDW + h * DKV + d]);
            sWo[d * WSTR + i] = f2bf(Wo[(h * DKV + i) * HH + d]);
        }
        __syncthreads();

        for (int jb = w; jb < 2 * NQT; jb += NWAVE) {
            const int   isV  = jb >= NQT;
            const int   tile = isV ? jb - NQT : jb;
            const float* X   = isV ? v : k;
            const short* sW  = isV ? sWv : sWk;
            int r = tile * 16 + L15; if (r > TT - 1) r = TT - 1;
            short8 afr[2];
            #pragma unroll
            for (int kt = 0; kt < 2; ++kt) {
                const float* px = X + xbase + (long)r * HH + kt * 32 + quad * 8;
                const float4 x0 = *(const float4*)px;
                const float4 x1 = *(const float4*)(px + 4);
                short8 a;
                a[0]=f2bf(x0.x); a[1]=f2bf(x0.y); a[2]=f2bf(x0.z); a[3]=f2bf(x0.w);
                a[4]=f2bf(x1.x); a[5]=f2bf(x1.y); a[6]=f2bf(x1.z); a[7]=f2bf(x1.w);
                afr[kt] = a;
            }
            #pragma unroll
            for (int nt = 0; nt < 4; ++nt) {
                f32x4 c; c[0]=0.f; c[1]=0.f; c[2]=0.f; c[3]=0.f;
                #pragma unroll
                for (int kt = 0; kt < 2; ++kt) {
                    const short8 bfr = *(const short8*)&sW[(nt*16 + L15) * WSTR + kt*32 + quad*8];
                    c = MFMA32(afr[kt], bfr, c);
                }
                #pragma unroll
                for (int rr = 0; rr < 4; ++rr) {
                    const int s = tile*16 + quad*4 + rr;
                    if (s < TT) {
                        const short bv = f2bf(c[rr]);
                        const int d = nt*16 + L15;
                        if (isV) sVT[d * VSTR + s] = bv;
                        else     sK [s * KSTR + d] = bv;
                    }
                }
            }
        }
        __syncthreads();

        for (int ti = 0; ti < nMy; ++ti) {
            const int tile = myT[ti];
            short8 qa[2];
            {
                int r = tile * 16 + L15; if (r > TT - 1) r = TT - 1;
                short8 afr[2];
                #pragma unroll
                for (int kt = 0; kt < 2; ++kt) {
                    const float* px = q + xbase + (long)r * HH + kt * 32 + quad * 8;
                    const float4 x0 = *(const float4*)px;
                    const float4 x1 = *(const float4*)(px + 4);
                    short8 a;
                    a[0]=f2bf(x0.x); a[1]=f2bf(x0.y); a[2]=f2bf(x0.z); a[3]=f2bf(x0.w);
                    a[4]=f2bf(x1.x); a[5]=f2bf(x1.y); a[6]=f2bf(x1.z); a[7]=f2bf(x1.w);
                    afr[kt] = a;
                }
                #pragma unroll
                for (int nt = 0; nt < 4; ++nt) {
                    f32x4 c; c[0]=0.f; c[1]=0.f; c[2]=0.f; c[3]=0.f;
                    #pragma unroll
                    for (int kt = 0; kt < 2; ++kt) {
                        const short8 bfr = *(const short8*)&sWq[(nt*16 + L15) * WSTR + kt*32 + quad*8];
                        c = MFMA32(afr[kt], bfr, c);
                    }
                    #pragma unroll
                    for (int rr = 0; rr < 4; ++rr)
                        sScrF[w][(quad*4+rr)*KSTR + nt*16 + L15] = f2bf(c[rr] * 0.125f);
                }
                LGKM_BAR();
                qa[0] = *(const short8*)&sScrF[w][L15*KSTR + quad*8];
                qa[1] = *(const short8*)&sScrF[w][L15*KSTR + 32 + quad*8];
            }

            float m[4] = {-3e38f, -3e38f, -3e38f, -3e38f};
            float l[4] = {0.f, 0.f, 0.f, 0.f};
            f32x4 o[4];
            #pragma unroll
            for (int nt = 0; nt < 4; ++nt) { o[nt][0]=0.f; o[nt][1]=0.f; o[nt][2]=0.f; o[nt][3]=0.f; }

            for (int st = 0; st < NST; ++st) {
                f32x4 s0, s1;
                s0[0]=0.f;s0[1]=0.f;s0[2]=0.f;s0[3]=0.f;
                s1[0]=0.f;s1[1]=0.f;s1[2]=0.f;s1[3]=0.f;
                #pragma unroll
                for (int kt = 0; kt < 2; ++kt) {
                    const short8 b0 = *(const short8*)&sK[(st*32      + L15) * KSTR + kt*32 + quad*8];
                    const short8 b1 = *(const short8*)&sK[(st*32 + 16 + L15) * KSTR + kt*32 + quad*8];
                    s0 = MFMA32(qa[kt], b0, s0);
                    s1 = MFMA32(qa[kt], b1, s1);
                }
                if (st == NST - 1) {
                    if (L15 >= 12) { s0[0]=-1e38f; s0[1]=-1e38f; s0[2]=-1e38f; s0[3]=-1e38f; }
                    s1[0]=-1e38f; s1[1]=-1e38f; s1[2]=-1e38f; s1[3]=-1e38f;
                }
                float corr[4];
                #pragma unroll
                for (int rr = 0; rr < 4; ++rr) {
                    float t = fmaxf(s0[rr], s1[rr]);
                    t = fmaxf(t, __shfl_xor(t, 1));
                    t = fmaxf(t, __shfl_xor(t, 2));
                    t = fmaxf(t, __shfl_xor(t, 4));
                    t = fmaxf(t, __shfl_xor(t, 8));
                    const float mn = fmaxf(m[rr], t);
                    corr[rr] = __expf(m[rr] - mn);
                    m[rr] = mn;
                    const float p0 = __expf(s0[rr] - mn);
                    const float p1 = __expf(s1[rr] - mn);
                    float rs = p0 + p1;
                    rs += __shfl_xor(rs, 1);
                    rs += __shfl_xor(rs, 2);
                    rs += __shfl_xor(rs, 4);
                    rs += __shfl_xor(rs, 8);
                    l[rr] = l[rr] * corr[rr] + rs;
                    sScrF[w][(quad*4+rr)*KSTR + L15]      = f2bf(p0);
                    sScrF[w][(quad*4+rr)*KSTR + 16 + L15] = f2bf(p1);
                }
                #pragma unroll
                for (int nt = 0; nt < 4; ++nt) {
                    o[nt][0] *= corr[0]; o[nt][1] *= corr[1];
                    o[nt][2] *= corr[2]; o[nt][3] *= corr[3];
                }
                LGKM_BAR();
                const short8 pa = *(const short8*)&sScrF[w][L15*KSTR + quad*8];
                #pragma unroll
                for (int nt = 0; nt < 4; ++nt) {
                    const short8 vb = *(const short8*)&sVT[(nt*16 + L15) * VSTR + st*32 + quad*8];
                    o[nt] = MFMA32(pa, vb, o[nt]);
                }
            }

            float linv[4];
            #pragma unroll
            for (int rr = 0; rr < 4; ++rr) linv[rr] = 1.f / l[rr];
            #pragma unroll
            for (int nt = 0; nt < 4; ++nt)
                #pragma unroll
                for (int rr = 0; rr < 4; ++rr)
                    sScrF[w][(quad*4+rr)*KSTR + nt*16 + L15] = f2bf(o[nt][rr] * linv[rr]);
            LGKM_BAR();
            const short8 oa0 = *(const short8*)&sScrF[w][L15*KSTR + quad*8];
            const short8 oa1 = *(const short8*)&sScrF[w][L15*KSTR + 32 + quad*8];
            #pragma unroll
            for (int nt = 0; nt < 4; ++nt) {
                const short8 w0 = *(const short8*)&sWo[(nt*16 + L15) * WSTR + quad*8];
                const short8 w1 = *(const short8*)&sWo[(nt*16 + L15) * WSTR + 32 + quad*8];
                y[ti][nt] = MFMA32(oa0, w0, y[ti][nt]);
                y[ti][nt] = MFMA32(oa1, w1, y[ti][nt]);
            }
        }
    }

    for (int ti = 0; ti < nMy; ++ti) {
        const int tile = myT[ti];
        #pragma unroll
        for (int nt = 0; nt < 4; ++nt)
            #pragma unroll
            for (int rr = 0; rr < 4; ++rr) {
                const int row = tile*16 + quad*4 + rr;
                if (row < TT)
                    out[xbase + (long)row * HH + nt*16 + L15] = y[ti][nt][rr];
            }
    }
}

extern "C" void kernel_launch(void* const* d_in, const int* in_sizes, int n_in,
                              void* d_out, int out_size, void* d_ws, size_t ws_size,
                              hipStream_t stream) {
    const float* q  = (const float*)d_in[0];
    const float* k  = (const float*)d_in[1];
    const float* v  = (const float*)d_in[2];
    const float* Wq = (const float*)d_in[3];
    const float* Wk = (const float*)d_in[4];
    const float* Wv = (const float*)d_in[5];
    const float* Wo = (const float*)d_in[6];
    float* out = (float*)d_out;

    if (ws_size >= WS_BYTES) {
        unsigned short* ws = (unsigned short*)d_ws;
        wfrag_kernel<<<160, 64, 0, stream>>>(Wq, Wk, Wv, Wo, ws);
        attn4<<<NB * NJ, 512, 0, stream>>>(q, k, v, ws, out);
    } else {
        mha_mfma<<<NB * NJ, 512, 0, stream>>>(q, k, v, Wq, Wk, Wv, Wo, out);
    }
}

// Round 2
// 293.755 us; speedup vs baseline: 1.3394x; 1.3394x over previous
//
#include <hip/hip_runtime.h>
#include <hip/hip_bf16.h>

// Problem constants
#define NB 16
#define SS 7500
#define HH 64
#define TT 300
#define NHEAD 4
#define DKV 64
#define NJ 25
#define HDW 256
#define NQT 19
#define NST 10       // s-tiles of 32

typedef __attribute__((ext_vector_type(8))) short short8;
typedef __attribute__((ext_vector_type(4))) short s16x4;
typedef __attribute__((ext_vector_type(4))) float f32x4;

__device__ inline short f2bf(float f) {
    union { float f; unsigned u; } x; x.f = f;
    unsigned u = x.u + 0x7FFFu + ((x.u >> 16) & 1u);
    return (short)(u >> 16);
}
__device__ inline unsigned pk2(float a, float b) {  // packed fp32x2 -> bf16x2
    __hip_bfloat162 h = __float22bfloat162_rn(make_float2(a, b));
    union { __hip_bfloat162 h; unsigned u; } c; c.h = h; return c.u;
}
#define MFMA32(a, b, c) __builtin_amdgcn_mfma_f32_16x16x32_bf16((a), (b), (c), 0, 0, 0)
#define LGKM_BAR() asm volatile("s_waitcnt lgkmcnt(0)" ::: "memory")

// 16x16x16 bf16 MFMA: operand k-granularity quad*4+i == C-frag row granularity,
// so all P/Q'/O relayouts are in-lane packs (no LDS scratch, no shuffles).
__device__ __forceinline__ f32x4 MFMA16(s16x4 a, s16x4 b, f32x4 c) {
#if __has_builtin(__builtin_amdgcn_mfma_f32_16x16x16bf16_1k)
    return __builtin_amdgcn_mfma_f32_16x16x16bf16_1k(a, b, c, 0, 0, 0);
#else
    // zero-padded K=32 fallback: A/B k-slots line up, upper half contributes 0
    short8 a8 = {a[0], a[1], a[2], a[3], 0, 0, 0, 0};
    short8 b8 = {b[0], b[1], b[2], b[3], 0, 0, 0, 0};
    return MFMA32(a8, b8, c);
#endif
}

__device__ __forceinline__ s16x4 lo4(short8 x) { return __builtin_shufflevector(x, x, 0, 1, 2, 3); }
__device__ __forceinline__ s16x4 hi4(short8 x) { return __builtin_shufflevector(x, x, 4, 5, 6, 7); }
__device__ __forceinline__ s16x4 pks4(unsigned a, unsigned b) {
    union { uint2 u; s16x4 s; } c; c.u.x = a; c.u.y = b; return c.s;
}
__device__ __forceinline__ short8 packx(const float* px) {
    const float4 x0 = *(const float4*)px;
    const float4 x1 = *(const float4*)(px + 4);
    union { uint4 u; short8 s; } cv;
    cv.u.x = pk2(x0.x, x0.y); cv.u.y = pk2(x0.z, x0.w);
    cv.u.z = pk2(x1.x, x1.y); cv.u.w = pk2(x1.z, x1.w);
    return cv.s;
}

// ws layout (bf16 units): QKV B-frags (96 frags x 512 shorts) + Wo K=16 frags
// (64 frags x 256 shorts). 131072 bytes total.
#define WS_BYTES ((size_t)65536 * 2)
#define WOBASE 49152

// ---------------- A0: weights -> bf16 fragment arrays ----------------
// f<96: {Wq,Wk,Wv}[matid=f/32], nt=(f%32)/2, kt=f%2; 16x16x32 frag, ld=256,K=64.
//       (A-frag and B-frag lane maps are identical, so these serve both roles.)
// f>=96: Wo K=16 frags, g=f-96: nt=g&3 (out-col tile), kt=g>>2 (K-chunk of 16).
__global__ void wfrag_kernel(const float* __restrict__ Wq, const float* __restrict__ Wk,
                             const float* __restrict__ Wv, const float* __restrict__ Wo,
                             unsigned short* __restrict__ ws) {
    const int f = blockIdx.x;
    const int lane = threadIdx.x;
    const int L15 = lane & 15, quad = lane >> 4;
    if (f < 96) {
        const int matid = f >> 5, nt = (f & 31) >> 1, kt = f & 1;
        const float* W = matid == 0 ? Wq : (matid == 1 ? Wk : Wv);
        const int n = nt * 16 + L15;
        unsigned short* dst = ws + f * 512 + lane * 8;
        #pragma unroll
        for (int i = 0; i < 8; ++i)
            dst[i] = (unsigned short)f2bf(W[(kt * 32 + quad * 8 + i) * HDW + n]);
    } else {
        const int g = f - 96, nt = g & 3, kt = g >> 2;
        const int n = nt * 16 + L15;
        unsigned short* dst = ws + WOBASE + g * 256 + lane * 4;
        #pragma unroll
        for (int i = 0; i < 4; ++i)
            dst[i] = (unsigned short)f2bf(Wo[(kt * 16 + quad * 4 + i) * HH + n]);
    }
}

// ---------------- fully fused: proj + attention + out-proj ----------------
// 640 threads (10 waves), LDS 79.4KB, 1 block/CU, NO register cap beyond
// launchability (~170) -- the R1 variant's __launch_bounds__(512,4) forced a
// 128-reg budget and spilled all accumulators to scratch (517MB WRITE_SIZE).
// sK[row 0..299][64]: K'^T rows; 16-short blocks XOR-swizzled by (row&3).
// sV[d 0..63][320]: V'^T; blocks (st*2 + quad>>1) XOR (d&3).
// Both read (b128) and write (b64) patterns are at the structural bank minimum.

__device__ __forceinline__ void qproj(const float* __restrict__ qg, long xbase,
                                      const unsigned short* __restrict__ wf,
                                      int h, int t, int L15, int quad, int lane,
                                      s16x4* qa) {
    int r = t * 16 + L15; if (r > TT - 1) r = TT - 1;
    const float* px = qg + xbase + (long)r * HH + quad * 8;
    const short8 xf0 = packx(px);
    const short8 xf1 = packx(px + 32);
    #pragma unroll
    for (int ntl = 0; ntl < 4; ++ntl) {
        const short8 b0 = *(const short8*)&wf[((h * 4 + ntl) * 2 + 0) * 512 + lane * 8];
        const short8 b1 = *(const short8*)&wf[((h * 4 + ntl) * 2 + 1) * 512 + lane * 8];
        f32x4 c = {0.f, 0.f, 0.f, 0.f};
        c = MFMA32(b0, xf0, c);   // A=W (swapped) => C = Q'^T[d'][q], q on L15
        c = MFMA32(b1, xf1, c);
        // in-lane pack to B-frag for K=16 QK (scale 1/8 folded)
        qa[ntl] = pks4(pk2(c[0] * 0.125f, c[1] * 0.125f),
                       pk2(c[2] * 0.125f, c[3] * 0.125f));
    }
}

__device__ __forceinline__ void attn_pass2(const unsigned short* __restrict__ sK,
                                           const unsigned short* __restrict__ sV,
                                           const s16x4 qa[2][4], f32x4 oT[2][4],
                                           float* __restrict__ lsum,
                                           int L15, int quad) {
    for (int st = 0; st < NST; ++st) {
        s16x4 pt[2][2];
        #pragma unroll
        for (int rh = 0; rh < 2; ++rh) {
            int row = st * 32 + rh * 16 + L15; if (row > TT - 1) row = TT - 1;
            const int rb = row * 64 + ((quad & 1) << 3);
            const short8 k0 = *(const short8*)&sK[rb + ((((quad >> 1) | 0) ^ (row & 3)) << 4)];
            const short8 k1 = *(const short8*)&sK[rb + ((((quad >> 1) | 2) ^ (row & 3)) << 4)];
            #pragma unroll
            for (int su = 0; su < 2; ++su) {
                f32x4 c = {0.f, 0.f, 0.f, 0.f};
                c = MFMA16(lo4(k0), qa[su][0], c);
                c = MFMA16(hi4(k0), qa[su][1], c);
                c = MFMA16(lo4(k1), qa[su][2], c);
                c = MFMA16(hi4(k1), qa[su][3], c);
                if (st == NST - 1) {      // mask s >= 300 (s = 288+rh*16+quad*4+rr)
                    if (rh == 1 || quad == 3) {
                        c[0] = -1e38f; c[1] = -1e38f; c[2] = -1e38f; c[3] = -1e38f;
                    }
                }
                // fixed-max softmax p=exp(s-16); exact after 1/l
                const float p0 = __expf(c[0] - 16.f);
                const float p1 = __expf(c[1] - 16.f);
                const float p2 = __expf(c[2] - 16.f);
                const float p3 = __expf(c[3] - 16.f);
                lsum[su] += (p0 + p1) + (p2 + p3);
                pt[su][rh] = pks4(pk2(p0, p1), pk2(p2, p3));   // in-lane B-frag
            }
        }
        #pragma unroll
        for (int nt = 0; nt < 4; ++nt) {
            const int d = nt * 16 + L15;
            const int blk = ((st << 1) | (quad >> 1)) ^ (d & 3);
            const short8 vp = *(const short8*)&sV[d * 320 + (blk << 4) + ((quad & 1) << 3)];
            #pragma unroll
            for (int su = 0; su < 2; ++su) {
                oT[su][nt] = MFMA16(lo4(vp), pt[su][0], oT[su][nt]);
                oT[su][nt] = MFMA16(hi4(vp), pt[su][1], oT[su][nt]);
            }
        }
    }
}

__device__ __forceinline__ void epilogue(const unsigned short* __restrict__ wf, int h,
                                         float lsum, const f32x4* oT, f32x4* y, int lane) {
    lsum += __shfl_xor(lsum, 16);
    lsum += __shfl_xor(lsum, 32);
    const float linv = 1.f / lsum;
    s16x4 oa[4];
    #pragma unroll
    for (int nt = 0; nt < 4; ++nt)     // in-lane A-frag pack (K=16 chunks of d)
        oa[nt] = pks4(pk2(oT[nt][0] * linv, oT[nt][1] * linv),
                      pk2(oT[nt][2] * linv, oT[nt][3] * linv));
    #pragma unroll
    for (int nc = 0; nc < 4; ++nc) {
        #pragma unroll
        for (int kc = 0; kc < 4; ++kc) {
            const s16x4 wb = *(const s16x4*)&wf[WOBASE + (((h * 4 + kc) * 4 + nc) << 8) + (lane << 2)];
            y[nc] = MFMA16(oa[kc], wb, y[nc]);
        }
    }
}

__device__ __forceinline__ void store_tile(float* __restrict__ out, long xbase, int tile,
                                           const f32x4* y, int L15, int quad) {
    #pragma unroll
    for (int nc = 0; nc < 4; ++nc)
        #pragma unroll
        for (int rr = 0; rr < 4; ++rr) {
            const int row = tile * 16 + quad * 4 + rr;
            if (row < TT)
                out[xbase + (long)row * HH + nc * 16 + L15] = y[nc][rr];
        }
}

__global__ __launch_bounds__(640, 1)
void attn5(const float* __restrict__ q, const float* __restrict__ k,
           const float* __restrict__ v, const unsigned short* __restrict__ wf,
           float* __restrict__ out)
{
    __shared__ __align__(16) unsigned short sK[19200];   // 38400 B
    __shared__ __align__(16) unsigned short sV[20480];   // 40960 B

    const int tid = threadIdx.x;
    const int w = tid >> 6, lane = tid & 63;
    const int L15 = lane & 15, quad = lane >> 4;
    const int bj = blockIdx.x;
    const int b = bj / NJ, j = bj % NJ;
    const long xbase = ((long)b * SS + (long)j * TT) * HH;

    // zero V pad (logical s 288..319 of st=9; valid parts rewritten each head)
    for (int i = tid; i < 2048; i += 640) {
        const int d = i >> 5, off = 288 + (i & 31);
        const int blk = (off >> 4) ^ (d & 3);
        sV[d * 320 + (blk << 4) + (off & 15)] = 0;
    }

    // wave w owns q-tiles 2w and 2w+1 (wave 9's second tile is a masked dummy)
    f32x4 y[2][4];
    #pragma unroll
    for (int sl = 0; sl < 2; ++sl)
        #pragma unroll
        for (int n = 0; n < 4; ++n) { y[sl][n][0]=0.f; y[sl][n][1]=0.f; y[sl][n][2]=0.f; y[sl][n][3]=0.f; }

    for (int h = 0; h < NHEAD; ++h) {
        __syncthreads();   // prior head's sK/sV readers done (also orders init)

        // ---- K'/V' projection into LDS: 38 jobs of 16 rows over 10 waves ----
        for (int jb = w; jb < 38; jb += 10) {
            const int isV = jb >= 19;
            const int t = isV ? jb - 19 : jb;
            const float* X = isV ? v : k;
            const unsigned short* mb = wf + (isV ? 2 : 1) * 16384;
            int r = t * 16 + L15; if (r > TT - 1) r = TT - 1;
            const float* px = X + xbase + (long)r * HH + quad * 8;
            const short8 xf0 = packx(px);
            const short8 xf1 = packx(px + 32);
            if (!isV) {
                const int s = t * 16 + L15;   // unclamped store row
                #pragma unroll
                for (int ntl = 0; ntl < 4; ++ntl) {
                    const short8 b0 = *(const short8*)&mb[((h * 4 + ntl) * 2 + 0) * 512 + lane * 8];
                    const short8 b1 = *(const short8*)&mb[((h * 4 + ntl) * 2 + 1) * 512 + lane * 8];
                    f32x4 c = {0.f, 0.f, 0.f, 0.f};
                    c = MFMA32(b0, xf0, c);   // A=W => C = K'^T[d'][s], s on L15
                    c = MFMA32(b1, xf1, c);
                    if (s < TT) {
                        uint2 pkd; pkd.x = pk2(c[0], c[1]); pkd.y = pk2(c[2], c[3]);
                        const int pp = ntl >> 1, oo = ntl & 1;
                        const int blk = ((pp << 1) | (quad >> 1)) ^ (s & 3);
                        *(uint2*)&sK[s * 64 + (blk << 4) + ((quad & 1) << 3) + (oo << 2)] = pkd;
                    }
                }
            } else {
                const int sb = t * 16 + quad * 4;
                const int stv = t >> 1, rhv = t & 1;
                #pragma unroll
                for (int ntl = 0; ntl < 4; ++ntl) {
                    const short8 b0 = *(const short8*)&mb[((h * 4 + ntl) * 2 + 0) * 512 + lane * 8];
                    const short8 b1 = *(const short8*)&mb[((h * 4 + ntl) * 2 + 1) * 512 + lane * 8];
                    f32x4 c = {0.f, 0.f, 0.f, 0.f};
                    c = MFMA32(xf0, b0, c);   // A=x => C = V'[s][d], d on L15
                    c = MFMA32(xf1, b1, c);
                    if (sb < TT) {
                        const int d = ntl * 16 + L15;
                        uint2 pkd; pkd.x = pk2(c[0], c[1]); pkd.y = pk2(c[2], c[3]);
                        const int blk = ((stv << 1) | (quad >> 1)) ^ (d & 3);
                        *(uint2*)&sV[d * 320 + (blk << 4) + ((quad & 1) << 3) + (rhv << 2)] = pkd;
                    }
                }
            }
        }

        // ---- Q' for this wave's tiles (overlaps LDS write drain; no LDS used) ----
        s16x4 qa[2][4];
        qproj(q, xbase, wf, h, 2 * w + 0, L15, quad, lane, qa[0]);
        qproj(q, xbase, wf, h, 2 * w + 1, L15, quad, lane, qa[1]);

        __syncthreads();   // sK/sV complete

        // ---- attention: joint 2 q-tiles, barrier-free st loop ----
        f32x4 oT[2][4]; float ls[2] = {0.f, 0.f};
        #pragma unroll
        for (int su = 0; su < 2; ++su)
            #pragma unroll
            for (int n = 0; n < 4; ++n) { oT[su][n][0]=0.f; oT[su][n][1]=0.f; oT[su][n][2]=0.f; oT[su][n][3]=0.f; }
        attn_pass2(sK, sV, qa, oT, ls, L15, quad);
        epilogue(wf, h, ls[0], oT[0], y[0], lane);
        epilogue(wf, h, ls[1], oT[1], y[1], lane);
    }

    store_tile(out, xbase, 2 * w + 0, y[0], L15, quad);   // tile 19 rows >=300: no store
    store_tile(out, xbase, 2 * w + 1, y[1], L15, quad);
}

// ================= Fallback (proven R2 kernel) for tiny ws =================
#define TPAD 320
#define KSTR 72
#define VSTR 328
#define WSTR 72
#define NWAVE 8
#define MAXTILE 3

__global__ __launch_bounds__(512, 1)
void mha_mfma(const float* __restrict__ q, const float* __restrict__ k,
              const float* __restrict__ v,
              const float* __restrict__ Wq, const float* __restrict__ Wk,
              const float* __restrict__ Wv, const float* __restrict__ Wo,
              float* __restrict__ out)
{
    __shared__ short sK [TPAD * KSTR];
    __shared__ short sVT[DKV * VSTR];
    __shared__ short sWq[DKV * WSTR];
    __shared__ short sWk[DKV * WSTR];
    __shared__ short sWv[DKV * WSTR];
    __shared__ short sWo[DKV * WSTR];
    __shared__ short sScrF[NWAVE][16 * KSTR];

    const int tid  = threadIdx.x;
    const int w    = tid >> 6;
    const int lane = tid & 63;
    const int L15  = lane & 15;
    const int quad = lane >> 4;

    const int blk = blockIdx.x;
    const int j = blk % NJ;
    const int b = blk / NJ;
    const long xbase = ((long)b * SS + (long)j * TT) * HH;

    for (int idx = tid; idx < 20 * KSTR; idx += 512) sK[300 * KSTR + idx] = 0;
    for (int idx = tid; idx < DKV * 32; idx += 512) {
        const int d = idx >> 5, c = 300 + (idx & 31);
        if (c < VSTR) sVT[d * VSTR + c] = 0;
    }

    int myT[MAXTILE]; int nMy = 0;
    for (int t = w; t < NQT; t += NWAVE) myT[nMy++] = t;

    f32x4 y[MAXTILE][4];
    #pragma unroll
    for (int a = 0; a < MAXTILE; ++a)
        #pragma unroll
        for (int n = 0; n < 4; ++n) { y[a][n][0]=0.f; y[a][n][1]=0.f; y[a][n][2]=0.f; y[a][n][3]=0.f; }

    for (int h = 0; h < NHEAD; ++h) {
        __syncthreads();
        for (int idx = tid; idx < 4096; idx += 512) {
            const int d = idx & 63;
            const int i = idx >> 6;
            sWq[d * WSTR + i] = f2bf(Wq[i * HDW + h * DKV + d]);
            sWk[d * WSTR + i] = f2bf(Wk[i * HDW + h * DKV + d]);
            sWv[d * WSTR + i] = f2bf(Wv[i * HDW + h * DKV + d]);
            sWo[d * WSTR + i] = f2bf(Wo[(h * DKV + i) * HH + d]);
        }
        __syncthreads();

        for (int jb = w; jb < 2 * NQT; jb += NWAVE) {
            const int   isV  = jb >= NQT;
            const int   tile = isV ? jb - NQT : jb;
            const float* X   = isV ? v : k;
            const short* sW  = isV ? sWv : sWk;
            int r = tile * 16 + L15; if (r > TT - 1) r = TT - 1;
            short8 afr[2];
            #pragma unroll
            for (int kt = 0; kt < 2; ++kt) {
                const float* px = X + xbase + (long)r * HH + kt * 32 + quad * 8;
                const float4 x0 = *(const float4*)px;
                const float4 x1 = *(const float4*)(px + 4);
                short8 a;
                a[0]=f2bf(x0.x); a[1]=f2bf(x0.y); a[2]=f2bf(x0.z); a[3]=f2bf(x0.w);
                a[4]=f2bf(x1.x); a[5]=f2bf(x1.y); a[6]=f2bf(x1.z); a[7]=f2bf(x1.w);
                afr[kt] = a;
            }
            #pragma unroll
            for (int nt = 0; nt < 4; ++nt) {
                f32x4 c; c[0]=0.f; c[1]=0.f; c[2]=0.f; c[3]=0.f;
                #pragma unroll
                for (int kt = 0; kt < 2; ++kt) {
                    const short8 bfr = *(const short8*)&sW[(nt*16 + L15) * WSTR + kt*32 + quad*8];
                    c = MFMA32(afr[kt], bfr, c);
                }
                #pragma unroll
                for (int rr = 0; rr < 4; ++rr) {
                    const int s = tile*16 + quad*4 + rr;
                    if (s < TT) {
                        const short bv = f2bf(c[rr]);
                        const int d = nt*16 + L15;
                        if (isV) sVT[d * VSTR + s] = bv;
                        else     sK [s * KSTR + d] = bv;
                    }
                }
            }
        }
        __syncthreads();

        for (int ti = 0; ti < nMy; ++ti) {
            const int tile = myT[ti];
            short8 qa[2];
            {
                int r = tile * 16 + L15; if (r > TT - 1) r = TT - 1;
                short8 afr[2];
                #pragma unroll
                for (int kt = 0; kt < 2; ++kt) {
                    const float* px = q + xbase + (long)r * HH + kt * 32 + quad * 8;
                    const float4 x0 = *(const float4*)px;
                    const float4 x1 = *(const float4*)(px + 4);
                    short8 a;
                    a[0]=f2bf(x0.x); a[1]=f2bf(x0.y); a[2]=f2bf(x0.z); a[3]=f2bf(x0.w);
                    a[4]=f2bf(x1.x); a[5]=f2bf(x1.y); a[6]=f2bf(x1.z); a[7]=f2bf(x1.w);
                    afr[kt] = a;
                }
                #pragma unroll
                for (int nt = 0; nt < 4; ++nt) {
                    f32x4 c; c[0]=0.f; c[1]=0.f; c[2]=0.f; c[3]=0.f;
                    #pragma unroll
                    for (int kt = 0; kt < 2; ++kt) {
                        const short8 bfr = *(const short8*)&sWq[(nt*16 + L15) * WSTR + kt*32 + quad*8];
                        c = MFMA32(afr[kt], bfr, c);
                    }
                    #pragma unroll
                    for (int rr = 0; rr < 4; ++rr)
                        sScrF[w][(quad*4+rr)*KSTR + nt*16 + L15] = f2bf(c[rr] * 0.125f);
                }
                LGKM_BAR();
                qa[0] = *(const short8*)&sScrF[w][L15*KSTR + quad*8];
                qa[1] = *(const short8*)&sScrF[w][L15*KSTR + 32 + quad*8];
            }

            float m[4] = {-3e38f, -3e38f, -3e38f, -3e38f};
            float l[4] = {0.f, 0.f, 0.f, 0.f};
            f32x4 o[4];
            #pragma unroll
            for (int nt = 0; nt < 4; ++nt) { o[nt][0]=0.f; o[nt][1]=0.f; o[nt][2]=0.f; o[nt][3]=0.f; }

            for (int st = 0; st < NST; ++st) {
                f32x4 s0, s1;
                s0[0]=0.f;s0[1]=0.f;s0[2]=0.f;s0[3]=0.f;
                s1[0]=0.f;s1[1]=0.f;s1[2]=0.f;s1[3]=0.f;
                #pragma unroll
                for (int kt = 0; kt < 2; ++kt) {
                    const short8 b0 = *(const short8*)&sK[(st*32      + L15) * KSTR + kt*32 + quad*8];
                    const short8 b1 = *(const short8*)&sK[(st*32 + 16 + L15) * KSTR + kt*32 + quad*8];
                    s0 = MFMA32(qa[kt], b0, s0);
                    s1 = MFMA32(qa[kt], b1, s1);
                }
                if (st == NST - 1) {
                    if (L15 >= 12) { s0[0]=-1e38f; s0[1]=-1e38f; s0[2]=-1e38f; s0[3]=-1e38f; }
                    s1[0]=-1e38f; s1[1]=-1e38f; s1[2]=-1e38f; s1[3]=-1e38f;
                }
                float corr[4];
                #pragma unroll
                for (int rr = 0; rr < 4; ++rr) {
                    float t = fmaxf(s0[rr], s1[rr]);
                    t = fmaxf(t, __shfl_xor(t, 1));
                    t = fmaxf(t, __shfl_xor(t, 2));
                    t = fmaxf(t, __shfl_xor(t, 4));
                    t = fmaxf(t, __shfl_xor(t, 8));
                    const float mn = fmaxf(m[rr], t);
                    corr[rr] = __expf(m[rr] - mn);
                    m[rr] = mn;
                    const float p0 = __expf(s0[rr] - mn);
                    const float p1 = __expf(s1[rr] - mn);
                    float rs = p0 + p1;
                    rs += __shfl_xor(rs, 1);
                    rs += __shfl_xor(rs, 2);
                    rs += __shfl_xor(rs, 4);
                    rs += __shfl_xor(rs, 8);
                    l[rr] = l[rr] * corr[rr] + rs;
                    sScrF[w][(quad*4+rr)*KSTR + L15]      = f2bf(p0);
                    sScrF[w][(quad*4+rr)*KSTR + 16 + L15] = f2bf(p1);
                }
                #pragma unroll
                for (int nt = 0; nt < 4; ++nt) {
                    o[nt][0] *= corr[0]; o[nt][1] *= corr[1];
                    o[nt][2] *= corr[2]; o[nt][3] *= corr[3];
                }
                LGKM_BAR();
                const short8 pa = *(const short8*)&sScrF[w][L15*KSTR + quad*8];
                #pragma unroll
                for (int nt = 0; nt < 4; ++nt) {
                    const short8 vb = *(const short8*)&sVT[(nt*16 + L15) * VSTR + st*32 + quad*8];
                    o[nt] = MFMA32(pa, vb, o[nt]);
                }
            }

            float linv[4];
            #pragma unroll
            for (int rr = 0; rr < 4; ++rr) linv[rr] = 1.f / l[rr];
            #pragma unroll
            for (int nt = 0; nt < 4; ++nt)
                #pragma unroll
                for (int rr = 0; rr < 4; ++rr)
                    sScrF[w][(quad*4+rr)*KSTR + nt*16 + L15] = f2bf(o[nt][rr] * linv[rr]);
            LGKM_BAR();
            const short8 oa0 = *(const short8*)&sScrF[w][L15*KSTR + quad*8];
            const short8 oa1 = *(const short8*)&sScrF[w][L15*KSTR + 32 + quad*8];
            #pragma unroll
            for (int nt = 0; nt < 4; ++nt) {
                const short8 w0 = *(const short8*)&sWo[(nt*16 + L15) * WSTR + quad*8];
                const short8 w1 = *(const short8*)&sWo[(nt*16 + L15) * WSTR + 32 + quad*8];
                y[ti][nt] = MFMA32(oa0, w0, y[ti][nt]);
                y[ti][nt] = MFMA32(oa1, w1, y[ti][nt]);
            }
        }
    }

    for (int ti = 0; ti < nMy; ++ti) {
        const int tile = myT[ti];
        #pragma unroll
        for (int nt = 0; nt < 4; ++nt)
            #pragma unroll
            for (int rr = 0; rr < 4; ++rr) {
                const int row = tile*16 + quad*4 + rr;
                if (row < TT)
                    out[xbase + (long)row * HH + nt*16 + L15] = y[ti][nt][rr];
            }
    }
}

extern "C" void kernel_launch(void* const* d_in, const int* in_sizes, int n_in,
                              void* d_out, int out_size, void* d_ws, size_t ws_size,
                              hipStream_t stream) {
    const float* q  = (const float*)d_in[0];
    const float* k  = (const float*)d_in[1];
    const float* v  = (const float*)d_in[2];
    const float* Wq = (const float*)d_in[3];
    const float* Wk = (const float*)d_in[4];
    const float* Wv = (const float*)d_in[5];
    const float* Wo = (const float*)d_in[6];
    float* out = (float*)d_out;

    if (ws_size >= WS_BYTES) {
        unsigned short* ws = (unsigned short*)d_ws;
        wfrag_kernel<<<160, 64, 0, stream>>>(Wq, Wk, Wv, Wo, ws);
        attn5<<<NB * NJ, 640, 0, stream>>>(q, k, v, ws, out);
    } else {
        mha_mfma<<<NB * NJ, 512, 0, stream>>>(q, k, v, Wq, Wk, Wv, Wo, out);
    }
}

// Round 3
// 283.075 us; speedup vs baseline: 1.3899x; 1.0377x over previous
//
#include <hip/hip_runtime.h>
#include <hip/hip_bf16.h>

// Problem constants
#define NB 16
#define SS 7500
#define HH 64
#define TT 300
#define NHEAD 4
#define DKV 64
#define NJ 25
#define HDW 256
#define NQT 19
#define NST 10       // s-tiles of 32

typedef __attribute__((ext_vector_type(8))) short short8;
typedef __attribute__((ext_vector_type(4))) short s16x4;
typedef __attribute__((ext_vector_type(4))) float f32x4;

__device__ inline short f2bf(float f) {
    union { float f; unsigned u; } x; x.f = f;
    unsigned u = x.u + 0x7FFFu + ((x.u >> 16) & 1u);
    return (short)(u >> 16);
}
__device__ inline unsigned pk2(float a, float b) {  // packed fp32x2 -> bf16x2
    __hip_bfloat162 h = __float22bfloat162_rn(make_float2(a, b));
    union { __hip_bfloat162 h; unsigned u; } c; c.h = h; return c.u;
}
#define MFMA32(a, b, c) __builtin_amdgcn_mfma_f32_16x16x32_bf16((a), (b), (c), 0, 0, 0)
#define LGKM_BAR() asm volatile("s_waitcnt lgkmcnt(0)" ::: "memory")

// 16x16x16 bf16 MFMA (same issue cost as K=32 on gfx950 -- use ONLY where the
// in-lane relayout saving beats the wasted half-K: P->PV and O->Wo paths).
__device__ __forceinline__ f32x4 MFMA16(s16x4 a, s16x4 b, f32x4 c) {
#if __has_builtin(__builtin_amdgcn_mfma_f32_16x16x16bf16_1k)
    return __builtin_amdgcn_mfma_f32_16x16x16bf16_1k(a, b, c, 0, 0, 0);
#else
    short8 a8 = {a[0], a[1], a[2], a[3], 0, 0, 0, 0};
    short8 b8 = {b[0], b[1], b[2], b[3], 0, 0, 0, 0};
    return MFMA32(a8, b8, c);
#endif
}

__device__ __forceinline__ s16x4 lo4(short8 x) { return __builtin_shufflevector(x, x, 0, 1, 2, 3); }
__device__ __forceinline__ s16x4 hi4(short8 x) { return __builtin_shufflevector(x, x, 4, 5, 6, 7); }
__device__ __forceinline__ s16x4 pks4(unsigned a, unsigned b) {
    union { uint2 u; s16x4 s; } c; c.u.x = a; c.u.y = b; return c.s;
}
__device__ __forceinline__ short8 packx(const float* px) {
    const float4 x0 = *(const float4*)px;
    const float4 x1 = *(const float4*)(px + 4);
    union { uint4 u; short8 s; } cv;
    cv.u.x = pk2(x0.x, x0.y); cv.u.y = pk2(x0.z, x0.w);
    cv.u.z = pk2(x1.x, x1.y); cv.u.w = pk2(x1.z, x1.w);
    return cv.s;
}

// ws layout (bf16 units): QKV B-frags (96 frags x 512 shorts) + Wo K=16 frags
// (64 frags x 256 shorts). 131072 bytes total.
#define WS_BYTES ((size_t)65536 * 2)
#define WOBASE 49152

// ---------------- A0: weights -> bf16 fragment arrays ----------------
__global__ void wfrag_kernel(const float* __restrict__ Wq, const float* __restrict__ Wk,
                             const float* __restrict__ Wv, const float* __restrict__ Wo,
                             unsigned short* __restrict__ ws) {
    const int f = blockIdx.x;
    const int lane = threadIdx.x;
    const int L15 = lane & 15, quad = lane >> 4;
    if (f < 96) {
        const int matid = f >> 5, nt = (f & 31) >> 1, kt = f & 1;
        const float* W = matid == 0 ? Wq : (matid == 1 ? Wk : Wv);
        const int n = nt * 16 + L15;
        unsigned short* dst = ws + f * 512 + lane * 8;
        #pragma unroll
        for (int i = 0; i < 8; ++i)
            dst[i] = (unsigned short)f2bf(W[(kt * 32 + quad * 8 + i) * HDW + n]);
    } else {
        const int g = f - 96, nt = g & 3, kt = g >> 2;
        const int n = nt * 16 + L15;
        unsigned short* dst = ws + WOBASE + g * 256 + lane * 4;
        #pragma unroll
        for (int i = 0; i < 4; ++i)
            dst[i] = (unsigned short)f2bf(Wo[(kt * 16 + quad * 4 + i) * HH + n]);
    }
}

// ---------------- fully fused: proj + attention + out-proj ----------------
// 640 threads (10 waves), 1 block/CU. DOUBLE-BUFFERED sK/sV (155KB LDS):
// per head, each wave projects K'/V' of head h+1 into buf[cur^1] (VMEM-bound)
// then runs attention of head h from buf[cur] (MFMA/LDS-bound) -- one barrier
// per head; cross-wave skew overlaps HBM latency with matrix work.
// sK[row][64]: K'^T rows; 16-short blocks XOR-swizzled by (row&3).
// sV[d][320]: V'^T; blocks (st*2 + quad>>1) XOR (d&3).

__device__ __forceinline__ void proj_kv(const float* __restrict__ kg, const float* __restrict__ vg,
                                        long xbase, const unsigned short* __restrict__ wf, int hp,
                                        unsigned short* __restrict__ dK, unsigned short* __restrict__ dV,
                                        int w, int lane, int L15, int quad) {
    // 40 job slots over 10 waves (4 each); jb>=38 are naturally store-masked dummies
    #pragma unroll 2
    for (int i = 0; i < 4; ++i) {
        const int jb = w + 10 * i;
        const int isV = jb >= 19;
        const int t = isV ? jb - 19 : jb;
        const float* X = isV ? vg : kg;
        const unsigned short* mb = wf + (isV ? 2 : 1) * 16384;
        int r = t * 16 + L15; if (r > TT - 1) r = TT - 1;
        const float* px = X + xbase + (long)r * HH + quad * 8;
        const short8 xf0 = packx(px);
        const short8 xf1 = packx(px + 32);
        if (!isV) {
            const int s = t * 16 + L15;   // unclamped store row
            #pragma unroll
            for (int ntl = 0; ntl < 4; ++ntl) {
                const short8 b0 = *(const short8*)&mb[((hp * 4 + ntl) * 2 + 0) * 512 + lane * 8];
                const short8 b1 = *(const short8*)&mb[((hp * 4 + ntl) * 2 + 1) * 512 + lane * 8];
                f32x4 c = {0.f, 0.f, 0.f, 0.f};
                c = MFMA32(b0, xf0, c);   // A=W => C = K'^T[d'][s], s on L15
                c = MFMA32(b1, xf1, c);
                if (s < TT) {
                    uint2 pkd; pkd.x = pk2(c[0], c[1]); pkd.y = pk2(c[2], c[3]);
                    const int pp = ntl >> 1, oo = ntl & 1;
                    const int blk = ((pp << 1) | (quad >> 1)) ^ (s & 3);
                    *(uint2*)&dK[s * 64 + (blk << 4) + ((quad & 1) << 3) + (oo << 2)] = pkd;
                }
            }
        } else {
            const int sb = t * 16 + quad * 4;
            const int stv = t >> 1, rhv = t & 1;
            #pragma unroll
            for (int ntl = 0; ntl < 4; ++ntl) {
                const short8 b0 = *(const short8*)&mb[((hp * 4 + ntl) * 2 + 0) * 512 + lane * 8];
                const short8 b1 = *(const short8*)&mb[((hp * 4 + ntl) * 2 + 1) * 512 + lane * 8];
                f32x4 c = {0.f, 0.f, 0.f, 0.f};
                c = MFMA32(xf0, b0, c);   // A=x => C = V'[s][d], d on L15
                c = MFMA32(xf1, b1, c);
                if (sb < TT) {
                    const int d = ntl * 16 + L15;
                    uint2 pkd; pkd.x = pk2(c[0], c[1]); pkd.y = pk2(c[2], c[3]);
                    const int blk = ((stv << 1) | (quad >> 1)) ^ (d & 3);
                    *(uint2*)&dV[d * 320 + (blk << 4) + ((quad & 1) << 3) + (rhv << 2)] = pkd;
                }
            }
        }
    }
}

__device__ __forceinline__ void qproj_reg(const short8 qx[2],
                                          const unsigned short* __restrict__ wf,
                                          int h, s16x4* qa, int lane) {
    #pragma unroll
    for (int ntl = 0; ntl < 4; ++ntl) {
        const short8 b0 = *(const short8*)&wf[((h * 4 + ntl) * 2 + 0) * 512 + lane * 8];
        const short8 b1 = *(const short8*)&wf[((h * 4 + ntl) * 2 + 1) * 512 + lane * 8];
        f32x4 c = {0.f, 0.f, 0.f, 0.f};
        c = MFMA32(b0, qx[0], c);   // A=W (swapped) => C = Q'^T[d'][q], q on L15
        c = MFMA32(b1, qx[1], c);
        // in-lane pack to B-frag for K=16 QK (scale 1/8 folded)
        qa[ntl] = pks4(pk2(c[0] * 0.125f, c[1] * 0.125f),
                       pk2(c[2] * 0.125f, c[3] * 0.125f));
    }
}

__device__ __forceinline__ void attn_pass2(const unsigned short* __restrict__ sK,
                                           const unsigned short* __restrict__ sV,
                                           const s16x4 qa[2][4], f32x4 oT[2][4],
                                           float* __restrict__ lsum,
                                           int L15, int quad) {
    for (int st = 0; st < NST; ++st) {
        s16x4 pt[2][2];
        #pragma unroll
        for (int rh = 0; rh < 2; ++rh) {
            int row = st * 32 + rh * 16 + L15; if (row > TT - 1) row = TT - 1;
            const int rb = row * 64 + ((quad & 1) << 3);
            const short8 k0 = *(const short8*)&sK[rb + ((((quad >> 1) | 0) ^ (row & 3)) << 4)];
            const short8 k1 = *(const short8*)&sK[rb + ((((quad >> 1) | 2) ^ (row & 3)) << 4)];
            #pragma unroll
            for (int su = 0; su < 2; ++su) {
                f32x4 c = {0.f, 0.f, 0.f, 0.f};
                c = MFMA16(lo4(k0), qa[su][0], c);
                c = MFMA16(hi4(k0), qa[su][1], c);
                c = MFMA16(lo4(k1), qa[su][2], c);
                c = MFMA16(hi4(k1), qa[su][3], c);
                if (st == NST - 1) {      // mask s >= 300 (s = 288+rh*16+quad*4+rr)
                    if (rh == 1 || quad == 3) {
                        c[0] = -1e38f; c[1] = -1e38f; c[2] = -1e38f; c[3] = -1e38f;
                    }
                }
                // fixed-max softmax p=exp(s-16); exact after 1/l
                const float p0 = __expf(c[0] - 16.f);
                const float p1 = __expf(c[1] - 16.f);
                const float p2 = __expf(c[2] - 16.f);
                const float p3 = __expf(c[3] - 16.f);
                lsum[su] += (p0 + p1) + (p2 + p3);
                pt[su][rh] = pks4(pk2(p0, p1), pk2(p2, p3));   // in-lane B-frag
            }
        }
        #pragma unroll
        for (int nt = 0; nt < 4; ++nt) {
            const int d = nt * 16 + L15;
            const int blk = ((st << 1) | (quad >> 1)) ^ (d & 3);
            const short8 vp = *(const short8*)&sV[d * 320 + (blk << 4) + ((quad & 1) << 3)];
            #pragma unroll
            for (int su = 0; su < 2; ++su) {
                oT[su][nt] = MFMA16(lo4(vp), pt[su][0], oT[su][nt]);
                oT[su][nt] = MFMA16(hi4(vp), pt[su][1], oT[su][nt]);
            }
        }
    }
}

__device__ __forceinline__ void epilogue(const unsigned short* __restrict__ wf, int h,
                                         float lsum, const f32x4* oT, f32x4* y, int lane) {
    lsum += __shfl_xor(lsum, 16);
    lsum += __shfl_xor(lsum, 32);
    const float linv = 1.f / lsum;
    s16x4 oa[4];
    #pragma unroll
    for (int nt = 0; nt < 4; ++nt)     // in-lane A-frag pack (K=16 chunks of d)
        oa[nt] = pks4(pk2(oT[nt][0] * linv, oT[nt][1] * linv),
                      pk2(oT[nt][2] * linv, oT[nt][3] * linv));
    #pragma unroll
    for (int nc = 0; nc < 4; ++nc) {
        #pragma unroll
        for (int kc = 0; kc < 4; ++kc) {
            const s16x4 wb = *(const s16x4*)&wf[WOBASE + (((h * 4 + kc) * 4 + nc) << 8) + (lane << 2)];
            y[nc] = MFMA16(oa[kc], wb, y[nc]);
        }
    }
}

__device__ __forceinline__ void store_tile(float* __restrict__ out, long xbase, int tile,
                                           const f32x4* y, int L15, int quad) {
    #pragma unroll
    for (int nc = 0; nc < 4; ++nc)
        #pragma unroll
        for (int rr = 0; rr < 4; ++rr) {
            const int row = tile * 16 + quad * 4 + rr;
            if (row < TT)
                out[xbase + (long)row * HH + nc * 16 + L15] = y[nc][rr];
        }
}

__global__ __launch_bounds__(640, 3)
void attn6(const float* __restrict__ q, const float* __restrict__ k,
           const float* __restrict__ v, const unsigned short* __restrict__ wf,
           float* __restrict__ out)
{
    __shared__ __align__(16) unsigned short sK[2][19200];   // 2 x 38400 B
    __shared__ __align__(16) unsigned short sV[2][20480];   // 2 x 40960 B

    const int tid = threadIdx.x;
    const int w = tid >> 6, lane = tid & 63;
    const int L15 = lane & 15, quad = lane >> 4;
    const int bj = blockIdx.x;
    const int b = bj / NJ, j = bj % NJ;
    const long xbase = ((long)b * SS + (long)j * TT) * HH;

    // zero V pad (logical s 288..319 of st=9) for BOTH buffers
    for (int i = tid; i < 4096; i += 640) {
        const int bufi = i >> 11;
        const int ii = i & 2047;
        const int d = ii >> 5, off = 288 + (ii & 31);
        const int blk = (off >> 4) ^ (d & 3);
        sV[bufi][d * 320 + (blk << 4) + (off & 15)] = 0;
    }

    // hoisted q rows (packed bf16), head-invariant: wave w owns tiles 2w, 2w+1
    short8 qx[2][2];
    #pragma unroll
    for (int t = 0; t < 2; ++t) {
        int r = (2 * w + t) * 16 + L15; if (r > TT - 1) r = TT - 1;
        const float* px = q + xbase + (long)r * HH + quad * 8;
        qx[t][0] = packx(px);
        qx[t][1] = packx(px + 32);
    }

    f32x4 y[2][4];
    #pragma unroll
    for (int sl = 0; sl < 2; ++sl)
        #pragma unroll
        for (int n = 0; n < 4; ++n) { y[sl][n][0]=0.f; y[sl][n][1]=0.f; y[sl][n][2]=0.f; y[sl][n][3]=0.f; }

    proj_kv(k, v, xbase, wf, 0, sK[0], sV[0], w, lane, L15, quad);
    __syncthreads();

    for (int h = 0; h < NHEAD; ++h) {
        const int cur = h & 1;
        // project NEXT head into the other buffer; VMEM overlaps attention below
        if (h < NHEAD - 1)
            proj_kv(k, v, xbase, wf, h + 1, sK[cur ^ 1], sV[cur ^ 1], w, lane, L15, quad);

        s16x4 qa[2][4];
        qproj_reg(qx[0], wf, h, qa[0], lane);
        qproj_reg(qx[1], wf, h, qa[1], lane);

        f32x4 oT[2][4]; float ls[2] = {0.f, 0.f};
        #pragma unroll
        for (int su = 0; su < 2; ++su)
            #pragma unroll
            for (int n = 0; n < 4; ++n) { oT[su][n][0]=0.f; oT[su][n][1]=0.f; oT[su][n][2]=0.f; oT[su][n][3]=0.f; }
        attn_pass2(sK[cur], sV[cur], qa, oT, ls, L15, quad);
        epilogue(wf, h, ls[0], oT[0], y[0], lane);
        epilogue(wf, h, ls[1], oT[1], y[1], lane);

        __syncthreads();   // attn(h) readers done + proj(h+1) writers done
    }

    store_tile(out, xbase, 2 * w + 0, y[0], L15, quad);   // tile 19 rows >=300: no store
    store_tile(out, xbase, 2 * w + 1, y[1], L15, quad);
}

// ================= Fallback (proven R2 kernel) for tiny ws =================
#define TPAD 320
#define KSTR 72
#define VSTR 328
#define WSTR 72
#define NWAVE 8
#define MAXTILE 3

__global__ __launch_bounds__(512, 1)
void mha_mfma(const float* __restrict__ q, const float* __restrict__ k,
              const float* __restrict__ v,
              const float* __restrict__ Wq, const float* __restrict__ Wk,
              const float* __restrict__ Wv, const float* __restrict__ Wo,
              float* __restrict__ out)
{
    __shared__ short sK [TPAD * KSTR];
    __shared__ short sVT[DKV * VSTR];
    __shared__ short sWq[DKV * WSTR];
    __shared__ short sWk[DKV * WSTR];
    __shared__ short sWv[DKV * WSTR];
    __shared__ short sWo[DKV * WSTR];
    __shared__ short sScrF[NWAVE][16 * KSTR];

    const int tid  = threadIdx.x;
    const int w    = tid >> 6;
    const int lane = tid & 63;
    const int L15  = lane & 15;
    const int quad = lane >> 4;

    const int blk = blockIdx.x;
    const int j = blk % NJ;
    const int b = blk / NJ;
    const long xbase = ((long)b * SS + (long)j * TT) * HH;

    for (int idx = tid; idx < 20 * KSTR; idx += 512) sK[300 * KSTR + idx] = 0;
    for (int idx = tid; idx < DKV * 32; idx += 512) {
        const int d = idx >> 5, c = 300 + (idx & 31);
        if (c < VSTR) sVT[d * VSTR + c] = 0;
    }

    int myT[MAXTILE]; int nMy = 0;
    for (int t = w; t < NQT; t += NWAVE) myT[nMy++] = t;

    f32x4 y[MAXTILE][4];
    #pragma unroll
    for (int a = 0; a < MAXTILE; ++a)
        #pragma unroll
        for (int n = 0; n < 4; ++n) { y[a][n][0]=0.f; y[a][n][1]=0.f; y[a][n][2]=0.f; y[a][n][3]=0.f; }

    for (int h = 0; h < NHEAD; ++h) {
        __syncthreads();
        for (int idx = tid; idx < 4096; idx += 512) {
            const int d = idx & 63;
            const int i = idx >> 6;
            sWq[d * WSTR + i] = f2bf(Wq[i * HDW + h * DKV + d]);
            sWk[d * WSTR + i] = f2bf(Wk[i * HDW + h * DKV + d]);
            sWv[d * WSTR + i] = f2bf(Wv[i * HDW + h * DKV + d]);
            sWo[d * WSTR + i] = f2bf(Wo[(h * DKV + i) * HH + d]);
        }
        __syncthreads();

        for (int jb = w; jb < 2 * NQT; jb += NWAVE) {
            const int   isV  = jb >= NQT;
            const int   tile = isV ? jb - NQT : jb;
            const float* X   = isV ? v : k;
            const short* sW  = isV ? sWv : sWk;
            int r = tile * 16 + L15; if (r > TT - 1) r = TT - 1;
            short8 afr[2];
            #pragma unroll
            for (int kt = 0; kt < 2; ++kt) {
                const float* px = X + xbase + (long)r * HH + kt * 32 + quad * 8;
                const float4 x0 = *(const float4*)px;
                const float4 x1 = *(const float4*)(px + 4);
                short8 a;
                a[0]=f2bf(x0.x); a[1]=f2bf(x0.y); a[2]=f2bf(x0.z); a[3]=f2bf(x0.w);
                a[4]=f2bf(x1.x); a[5]=f2bf(x1.y); a[6]=f2bf(x1.z); a[7]=f2bf(x1.w);
                afr[kt] = a;
            }
            #pragma unroll
            for (int nt = 0; nt < 4; ++nt) {
                f32x4 c; c[0]=0.f; c[1]=0.f; c[2]=0.f; c[3]=0.f;
                #pragma unroll
                for (int kt = 0; kt < 2; ++kt) {
                    const short8 bfr = *(const short8*)&sW[(nt*16 + L15) * WSTR + kt*32 + quad*8];
                    c = MFMA32(afr[kt], bfr, c);
                }
                #pragma unroll
                for (int rr = 0; rr < 4; ++rr) {
                    const int s = tile*16 + quad*4 + rr;
                    if (s < TT) {
                        const short bv = f2bf(c[rr]);
                        const int d = nt*16 + L15;
                        if (isV) sVT[d * VSTR + s] = bv;
                        else     sK [s * KSTR + d] = bv;
                    }
                }
            }
        }
        __syncthreads();

        for (int ti = 0; ti < nMy; ++ti) {
            const int tile = myT[ti];
            short8 qa[2];
            {
                int r = tile * 16 + L15; if (r > TT - 1) r = TT - 1;
                short8 afr[2];
                #pragma unroll
                for (int kt = 0; kt < 2; ++kt) {
                    const float* px = q + xbase + (long)r * HH + kt * 32 + quad * 8;
                    const float4 x0 = *(const float4*)px;
                    const float4 x1 = *(const float4*)(px + 4);
                    short8 a;
                    a[0]=f2bf(x0.x); a[1]=f2bf(x0.y); a[2]=f2bf(x0.z); a[3]=f2bf(x0.w);
                    a[4]=f2bf(x1.x); a[5]=f2bf(x1.y); a[6]=f2bf(x1.z); a[7]=f2bf(x1.w);
                    afr[kt] = a;
                }
                #pragma unroll
                for (int nt = 0; nt < 4; ++nt) {
                    f32x4 c; c[0]=0.f; c[1]=0.f; c[2]=0.f; c[3]=0.f;
                    #pragma unroll
                    for (int kt = 0; kt < 2; ++kt) {
                        const short8 bfr = *(const short8*)&sWq[(nt*16 + L15) * WSTR + kt*32 + quad*8];
                        c = MFMA32(afr[kt], bfr, c);
                    }
                    #pragma unroll
                    for (int rr = 0; rr < 4; ++rr)
                        sScrF[w][(quad*4+rr)*KSTR + nt*16 + L15] = f2bf(c[rr] * 0.125f);
                }
                LGKM_BAR();
                qa[0] = *(const short8*)&sScrF[w][L15*KSTR + quad*8];
                qa[1] = *(const short8*)&sScrF[w][L15*KSTR + 32 + quad*8];
            }

            float m[4] = {-3e38f, -3e38f, -3e38f, -3e38f};
            float l[4] = {0.f, 0.f, 0.f, 0.f};
            f32x4 o[4];
            #pragma unroll
            for (int nt = 0; nt < 4; ++nt) { o[nt][0]=0.f; o[nt][1]=0.f; o[nt][2]=0.f; o[nt][3]=0.f; }

            for (int st = 0; st < NST; ++st) {
                f32x4 s0, s1;
                s0[0]=0.f;s0[1]=0.f;s0[2]=0.f;s0[3]=0.f;
                s1[0]=0.f;s1[1]=0.f;s1[2]=0.f;s1[3]=0.f;
                #pragma unroll
                for (int kt = 0; kt < 2; ++kt) {
                    const short8 b0 = *(const short8*)&sK[(st*32      + L15) * KSTR + kt*32 + quad*8];
                    const short8 b1 = *(const short8*)&sK[(st*32 + 16 + L15) * KSTR + kt*32 + quad*8];
                    s0 = MFMA32(qa[kt], b0, s0);
                    s1 = MFMA32(qa[kt], b1, s1);
                }
                if (st == NST - 1) {
                    if (L15 >= 12) { s0[0]=-1e38f; s0[1]=-1e38f; s0[2]=-1e38f; s0[3]=-1e38f; }
                    s1[0]=-1e38f; s1[1]=-1e38f; s1[2]=-1e38f; s1[3]=-1e38f;
                }
                float corr[4];
                #pragma unroll
                for (int rr = 0; rr < 4; ++rr) {
                    float t = fmaxf(s0[rr], s1[rr]);
                    t = fmaxf(t, __shfl_xor(t, 1));
                    t = fmaxf(t, __shfl_xor(t, 2));
                    t = fmaxf(t, __shfl_xor(t, 4));
                    t = fmaxf(t, __shfl_xor(t, 8));
                    const float mn = fmaxf(m[rr], t);
                    corr[rr] = __expf(m[rr] - mn);
                    m[rr] = mn;
                    const float p0 = __expf(s0[rr] - mn);
                    const float p1 = __expf(s1[rr] - mn);
                    float rs = p0 + p1;
                    rs += __shfl_xor(rs, 1);
                    rs += __shfl_xor(rs, 2);
                    rs += __shfl_xor(rs, 4);
                    rs += __shfl_xor(rs, 8);
                    l[rr] = l[rr] * corr[rr] + rs;
                    sScrF[w][(quad*4+rr)*KSTR + L15]      = f2bf(p0);
                    sScrF[w][(quad*4+rr)*KSTR + 16 + L15] = f2bf(p1);
                }
                #pragma unroll
                for (int nt = 0; nt < 4; ++nt) {
                    o[nt][0] *= corr[0]; o[nt][1] *= corr[1];
                    o[nt][2] *= corr[2]; o[nt][3] *= corr[3];
                }
                LGKM_BAR();
                const short8 pa = *(const short8*)&sScrF[w][L15*KSTR + quad*8];
                #pragma unroll
                for (int nt = 0; nt < 4; ++nt) {
                    const short8 vb = *(const short8*)&sVT[(nt*16 + L15) * VSTR + st*32 + quad*8];
                    o[nt] = MFMA32(pa, vb, o[nt]);
                }
            }

            float linv[4];
            #pragma unroll
            for (int rr = 0; rr < 4; ++rr) linv[rr] = 1.f / l[rr];
            #pragma unroll
            for (int nt = 0; nt < 4; ++nt)
                #pragma unroll
                for (int rr = 0; rr < 4; ++rr)
                    sScrF[w][(quad*4+rr)*KSTR + nt*16 + L15] = f2bf(o[nt][rr] * linv[rr]);
            LGKM_BAR();
            const short8 oa0 = *(const short8*)&sScrF[w][L15*KSTR + quad*8];
            const short8 oa1 = *(const short8*)&sScrF[w][L15*KSTR + 32 + quad*8];
            #pragma unroll
            for (int nt = 0; nt < 4; ++nt) {
                const short8 w0 = *(const short8*)&sWo[(nt*16 + L15) * WSTR + quad*8];
                const short8 w1 = *(const short8*)&sWo[(nt*16 + L15) * WSTR + 32 + quad*8];
                y[ti][nt] = MFMA32(oa0, w0, y[ti][nt]);
                y[ti][nt] = MFMA32(oa1, w1, y[ti][nt]);
            }
        }
    }

    for (int ti = 0; ti < nMy; ++ti) {
        const int tile = myT[ti];
        #pragma unroll
        for (int nt = 0; nt < 4; ++nt)
            #pragma unroll
            for (int rr = 0; rr < 4; ++rr) {
                const int row = tile*16 + quad*4 + rr;
                if (row < TT)
                    out[xbase + (long)row * HH + nt*16 + L15] = y[ti][nt][rr];
            }
    }
}

extern "C" void kernel_launch(void* const* d_in, const int* in_sizes, int n_in,
                              void* d_out, int out_size, void* d_ws, size_t ws_size,
                              hipStream_t stream) {
    const float* q  = (const float*)d_in[0];
    const float* k  = (const float*)d_in[1];
    const float* v  = (const float*)d_in[2];
    const float* Wq = (const float*)d_in[3];
    const float* Wk = (const float*)d_in[4];
    const float* Wv = (const float*)d_in[5];
    const float* Wo = (const float*)d_in[6];
    float* out = (float*)d_out;

    if (ws_size >= WS_BYTES) {
        unsigned short* ws = (unsigned short*)d_ws;
        wfrag_kernel<<<160, 64, 0, stream>>>(Wq, Wk, Wv, Wo, ws);
        attn6<<<NB * NJ, 640, 0, stream>>>(q, k, v, ws, out);
    } else {
        mha_mfma<<<NB * NJ, 512, 0, stream>>>(q, k, v, Wq, Wk, Wv, Wo, out);
    }
}

// Round 5
// 278.922 us; speedup vs baseline: 1.4106x; 1.0149x over previous
//
#include <hip/hip_runtime.h>
#include <hip/hip_bf16.h>

// Problem constants
#define NB 16
#define SS 7500
#define HH 64
#define TT 300
#define NHEAD 4
#define DKV 64
#define NJ 25
#define HDW 256
#define NQT 19
#define NST 10       // s-tiles of 32

typedef __attribute__((ext_vector_type(8))) short short8;
typedef __attribute__((ext_vector_type(4))) short s16x4;
typedef __attribute__((ext_vector_type(4))) float f32x4;

__device__ inline short f2bf(float f) {
    union { float f; unsigned u; } x; x.f = f;
    unsigned u = x.u + 0x7FFFu + ((x.u >> 16) & 1u);
    return (short)(u >> 16);
}
__device__ inline unsigned pk2(float a, float b) {  // packed fp32x2 -> bf16x2
    __hip_bfloat162 h = __float22bfloat162_rn(make_float2(a, b));
    union { __hip_bfloat162 h; unsigned u; } c; c.h = h; return c.u;
}
#define MFMA32(a, b, c) __builtin_amdgcn_mfma_f32_16x16x32_bf16((a), (b), (c), 0, 0, 0)
#define LGKM_BAR() asm volatile("s_waitcnt lgkmcnt(0)" ::: "memory")

__device__ __forceinline__ short8 pks8(unsigned a, unsigned b, unsigned c2, unsigned d) {
    union { uint4 u; short8 s; } c; c.u.x = a; c.u.y = b; c.u.z = c2; c.u.w = d; return c.s;
}
__device__ __forceinline__ short8 cat8(s16x4 a, s16x4 b) {
    return __builtin_shufflevector(a, b, 0, 1, 2, 3, 4, 5, 6, 7);
}
__device__ __forceinline__ short8 packx(const float* px) {
    const float4 x0 = *(const float4*)px;
    const float4 x1 = *(const float4*)(px + 4);
    union { uint4 u; short8 s; } cv;
    cv.u.x = pk2(x0.x, x0.y); cv.u.y = pk2(x0.z, x0.w);
    cv.u.z = pk2(x1.x, x1.y); cv.u.w = pk2(x1.z, x1.w);
    return cv.s;
}

// ws layout (bf16 units): QKV B-frags (96 frags x 512 shorts) + Wo K=16 frags
// (64 frags x 256 shorts). 131072 bytes total.
#define WS_BYTES ((size_t)65536 * 2)
#define WOBASE 49152

// ---------------- A0: weights -> bf16 fragment arrays ----------------
__global__ void wfrag_kernel(const float* __restrict__ Wq, const float* __restrict__ Wk,
                             const float* __restrict__ Wv, const float* __restrict__ Wo,
                             unsigned short* __restrict__ ws) {
    const int f = blockIdx.x;
    const int lane = threadIdx.x;
    const int L15 = lane & 15, quad = lane >> 4;
    if (f < 96) {
        const int matid = f >> 5, nt = (f & 31) >> 1, kt = f & 1;
        const float* W = matid == 0 ? Wq : (matid == 1 ? Wk : Wv);
        const int n = nt * 16 + L15;
        unsigned short* dst = ws + f * 512 + lane * 8;
        #pragma unroll
        for (int i = 0; i < 8; ++i)
            dst[i] = (unsigned short)f2bf(W[(kt * 32 + quad * 8 + i) * HDW + n]);
    } else {
        const int g = f - 96, nt = g & 3, kt = g >> 2;
        const int n = nt * 16 + L15;
        unsigned short* dst = ws + WOBASE + g * 256 + lane * 4;
        #pragma unroll
        for (int i = 0; i < 4; ++i)
            dst[i] = (unsigned short)f2bf(Wo[(kt * 16 + quad * 4 + i) * HH + n]);
    }
}

// ---------------- fully fused: proj + attention + out-proj ----------------
// 640 threads (10 waves), 1 block/CU (LDS 155KB forces it; launch_bounds(640,2)
// relaxes the VGPR cap to 256 -- free since LDS is the binding limit).
// KEY IDENTITY: MFMA32(cat(a1,a2), cat(b1,b2)) == MFMA16(a1,b1)+MFMA16(a2,b2)
// (slot-wise pairing; only the product SET matters) => all K=16 fragment pairs
// are concatenated in-lane and fed to K=32 MFMA: half the matrix-pipe cycles.
// K/V input rows are head-invariant: loaded+packed ONCE into registers.
// RACE FIX (R4 post-timing divergence): the sV pad-init writes linear slots
// 288..319 of each d-row; proj's t=18 V job writes slots 288..307. A
// __syncthreads() between init and proj_kv(0) is REQUIRED (R2 had it via the
// head-loop top barrier; the R3 restructure lost it; R4's reg-hoist made proj
// writes fast enough to lose the race on some replays).
// sK[row][64]: K'^T rows; 16-short blocks XOR-swizzled by (row&3).
// sV[d][320]: V'^T; blocks (st*2 + quad>>1) XOR (d&3).

__device__ __forceinline__ void proj_kv(const short8 xf[4][2],
                                        const unsigned short* __restrict__ wf, int hp,
                                        unsigned short* __restrict__ dK, unsigned short* __restrict__ dV,
                                        int w, int lane, int L15, int quad) {
    // 40 job slots over 10 waves (4 each); jb>=38 are naturally store-masked dummies
    #pragma unroll
    for (int i = 0; i < 4; ++i) {
        const int jb = w + 10 * i;
        const int isV = jb >= 19;
        const int t = isV ? jb - 19 : jb;
        const unsigned short* mb = wf + (isV ? 2 : 1) * 16384;
        if (!isV) {
            const int s = t * 16 + L15;   // unclamped store row
            #pragma unroll
            for (int ntl = 0; ntl < 4; ++ntl) {
                const short8 b0 = *(const short8*)&mb[((hp * 4 + ntl) * 2 + 0) * 512 + lane * 8];
                const short8 b1 = *(const short8*)&mb[((hp * 4 + ntl) * 2 + 1) * 512 + lane * 8];
                f32x4 c = {0.f, 0.f, 0.f, 0.f};
                c = MFMA32(b0, xf[i][0], c);   // A=W => C = K'^T[d'][s], s on L15
                c = MFMA32(b1, xf[i][1], c);
                if (s < TT) {
                    uint2 pkd; pkd.x = pk2(c[0], c[1]); pkd.y = pk2(c[2], c[3]);
                    const int pp = ntl >> 1, oo = ntl & 1;
                    const int blk = ((pp << 1) | (quad >> 1)) ^ (s & 3);
                    *(uint2*)&dK[s * 64 + (blk << 4) + ((quad & 1) << 3) + (oo << 2)] = pkd;
                }
            }
        } else {
            const int sb = t * 16 + quad * 4;
            const int stv = t >> 1, rhv = t & 1;
            #pragma unroll
            for (int ntl = 0; ntl < 4; ++ntl) {
                const short8 b0 = *(const short8*)&mb[((hp * 4 + ntl) * 2 + 0) * 512 + lane * 8];
                const short8 b1 = *(const short8*)&mb[((hp * 4 + ntl) * 2 + 1) * 512 + lane * 8];
                f32x4 c = {0.f, 0.f, 0.f, 0.f};
                c = MFMA32(xf[i][0], b0, c);   // A=x => C = V'[s][d], d on L15
                c = MFMA32(xf[i][1], b1, c);
                if (sb < TT) {
                    const int d = ntl * 16 + L15;
                    uint2 pkd; pkd.x = pk2(c[0], c[1]); pkd.y = pk2(c[2], c[3]);
                    const int blk = ((stv << 1) | (quad >> 1)) ^ (d & 3);
                    *(uint2*)&dV[d * 320 + (blk << 4) + ((quad & 1) << 3) + (rhv << 2)] = pkd;
                }
            }
        }
    }
}

// Q' projection -> two concatenated K=32 B-frags (qa8[0] pairs with sK's k0
// chunk, qa8[1] with k1); scale 1/8 folded.
__device__ __forceinline__ void qproj_reg(const short8 qx[2],
                                          const unsigned short* __restrict__ wf,
                                          int h, short8* qa8, int lane) {
    #pragma unroll
    for (int p = 0; p < 2; ++p) {
        unsigned pkv[4];
        #pragma unroll
        for (int hf = 0; hf < 2; ++hf) {
            const int ntl = 2 * p + hf;
            const short8 b0 = *(const short8*)&wf[((h * 4 + ntl) * 2 + 0) * 512 + lane * 8];
            const short8 b1 = *(const short8*)&wf[((h * 4 + ntl) * 2 + 1) * 512 + lane * 8];
            f32x4 c = {0.f, 0.f, 0.f, 0.f};
            c = MFMA32(b0, qx[0], c);   // A=W (swapped) => C = Q'^T[d'][q], q on L15
            c = MFMA32(b1, qx[1], c);
            pkv[2 * hf + 0] = pk2(c[0] * 0.125f, c[1] * 0.125f);
            pkv[2 * hf + 1] = pk2(c[2] * 0.125f, c[3] * 0.125f);
        }
        qa8[p] = pks8(pkv[0], pkv[1], pkv[2], pkv[3]);
    }
}

__device__ __forceinline__ void attn_pass2(const unsigned short* __restrict__ sK,
                                           const unsigned short* __restrict__ sV,
                                           const short8 qa8[2][2], f32x4 oT[2][4],
                                           float* __restrict__ lsum,
                                           int L15, int quad) {
    #pragma unroll 2
    for (int st = 0; st < NST; ++st) {
        unsigned ptw[2][4];
        #pragma unroll
        for (int rh = 0; rh < 2; ++rh) {
            int row = st * 32 + rh * 16 + L15; if (row > TT - 1) row = TT - 1;
            const int rb = row * 64 + ((quad & 1) << 3);
            const short8 k0 = *(const short8*)&sK[rb + ((((quad >> 1) | 0) ^ (row & 3)) << 4)];
            const short8 k1 = *(const short8*)&sK[rb + ((((quad >> 1) | 2) ^ (row & 3)) << 4)];
            #pragma unroll
            for (int su = 0; su < 2; ++su) {
                f32x4 c = {0.f, 0.f, 0.f, 0.f};
                __builtin_amdgcn_s_setprio(1);
                c = MFMA32(k0, qa8[su][0], c);
                c = MFMA32(k1, qa8[su][1], c);
                __builtin_amdgcn_s_setprio(0);
                if (st == NST - 1) {      // mask s >= 300 (s = 288+rh*16+quad*4+rr)
                    if (rh == 1 || quad == 3) {
                        c[0] = -1e38f; c[1] = -1e38f; c[2] = -1e38f; c[3] = -1e38f;
                    }
                }
                // fixed-max softmax p=exp(s-16); exact after 1/l
                const float p0 = __expf(c[0] - 16.f);
                const float p1 = __expf(c[1] - 16.f);
                const float p2 = __expf(c[2] - 16.f);
                const float p3 = __expf(c[3] - 16.f);
                lsum[su] += (p0 + p1) + (p2 + p3);
                ptw[su][2 * rh + 0] = pk2(p0, p1);
                ptw[su][2 * rh + 1] = pk2(p2, p3);
            }
        }
        const short8 pa0 = pks8(ptw[0][0], ptw[0][1], ptw[0][2], ptw[0][3]);
        const short8 pa1 = pks8(ptw[1][0], ptw[1][1], ptw[1][2], ptw[1][3]);
        #pragma unroll
        for (int nt = 0; nt < 4; ++nt) {
            const int d = nt * 16 + L15;
            const int blk = ((st << 1) | (quad >> 1)) ^ (d & 3);
            const short8 vp = *(const short8*)&sV[d * 320 + (blk << 4) + ((quad & 1) << 3)];
            __builtin_amdgcn_s_setprio(1);
            oT[0][nt] = MFMA32(vp, pa0, oT[0][nt]);
            oT[1][nt] = MFMA32(vp, pa1, oT[1][nt]);
            __builtin_amdgcn_s_setprio(0);
        }
    }
}

__device__ __forceinline__ void epilogue(const unsigned short* __restrict__ wf, int h,
                                         float lsum, const f32x4* oT, f32x4* y, int lane) {
    lsum += __shfl_xor(lsum, 16);
    lsum += __shfl_xor(lsum, 32);
    const float linv = 1.f / lsum;
    short8 oa8[2];   // in-lane A-frag packs, kc pairs concatenated to K=32
    #pragma unroll
    for (int p = 0; p < 2; ++p)
        oa8[p] = pks8(pk2(oT[2 * p][0] * linv, oT[2 * p][1] * linv),
                      pk2(oT[2 * p][2] * linv, oT[2 * p][3] * linv),
                      pk2(oT[2 * p + 1][0] * linv, oT[2 * p + 1][1] * linv),
                      pk2(oT[2 * p + 1][2] * linv, oT[2 * p + 1][3] * linv));
    #pragma unroll
    for (int nc = 0; nc < 4; ++nc) {
        #pragma unroll
        for (int p = 0; p < 2; ++p) {
            const s16x4 w0 = *(const s16x4*)&wf[WOBASE + (((h * 4 + 2 * p + 0) * 4 + nc) << 8) + (lane << 2)];
            const s16x4 w1 = *(const s16x4*)&wf[WOBASE + (((h * 4 + 2 * p + 1) * 4 + nc) << 8) + (lane << 2)];
            y[nc] = MFMA32(oa8[p], cat8(w0, w1), y[nc]);
        }
    }
}

__device__ __forceinline__ void store_tile(float* __restrict__ out, long xbase, int tile,
                                           const f32x4* y, int L15, int quad) {
    #pragma unroll
    for (int nc = 0; nc < 4; ++nc)
        #pragma unroll
        for (int rr = 0; rr < 4; ++rr) {
            const int row = tile * 16 + quad * 4 + rr;
            if (row < TT)
                out[xbase + (long)row * HH + nc * 16 + L15] = y[nc][rr];
        }
}

__global__ __launch_bounds__(640, 2)
void attn8(const float* __restrict__ q, const float* __restrict__ k,
           const float* __restrict__ v, const unsigned short* __restrict__ wf,
           float* __restrict__ out)
{
    __shared__ __align__(16) unsigned short sK[2][19200];   // 2 x 38400 B
    __shared__ __align__(16) unsigned short sV[2][20480];   // 2 x 40960 B

    const int tid = threadIdx.x;
    const int w = tid >> 6, lane = tid & 63;
    const int L15 = lane & 15, quad = lane >> 4;
    const int bj = blockIdx.x;
    const int b = bj / NJ, j = bj % NJ;
    const long xbase = ((long)b * SS + (long)j * TT) * HH;

    // zero V pad (logical s 288..319 of st=9) for BOTH buffers
    for (int i = tid; i < 4096; i += 640) {
        const int bufi = i >> 11;
        const int ii = i & 2047;
        const int d = ii >> 5, off = 288 + (ii & 31);
        const int blk = (off >> 4) ^ (d & 3);
        sV[bufi][d * 320 + (blk << 4) + (off & 15)] = 0;
    }

    // hoisted q rows (packed bf16), head-invariant: wave w owns tiles 2w, 2w+1
    short8 qx[2][2];
    #pragma unroll
    for (int t = 0; t < 2; ++t) {
        int r = (2 * w + t) * 16 + L15; if (r > TT - 1) r = TT - 1;
        const float* px = q + xbase + (long)r * HH + quad * 8;
        qx[t][0] = packx(px);
        qx[t][1] = packx(px + 32);
    }

    // hoisted K/V rows for this wave's 4 proj jobs (head-invariant)
    short8 xf[4][2];
    #pragma unroll
    for (int i = 0; i < 4; ++i) {
        const int jb = w + 10 * i;
        const int isV = jb >= 19;
        const int t = isV ? jb - 19 : jb;
        const float* X = isV ? v : k;
        int r = t * 16 + L15; if (r > TT - 1) r = TT - 1;
        const float* px = X + xbase + (long)r * HH + quad * 8;
        xf[i][0] = packx(px);
        xf[i][1] = packx(px + 32);
    }

    f32x4 y[2][4];
    #pragma unroll
    for (int sl = 0; sl < 2; ++sl)
        #pragma unroll
        for (int n = 0; n < 4; ++n) { y[sl][n][0]=0.f; y[sl][n][1]=0.f; y[sl][n][2]=0.f; y[sl][n][3]=0.f; }

    __syncthreads();   // RACE FIX: pad-init must be LDS-visible before proj writes

    proj_kv(xf, wf, 0, sK[0], sV[0], w, lane, L15, quad);
    __syncthreads();

    for (int h = 0; h < NHEAD; ++h) {
        const int cur = h & 1;
        // project NEXT head into the other buffer (pure reg->MFMA->LDS)
        if (h < NHEAD - 1)
            proj_kv(xf, wf, h + 1, sK[cur ^ 1], sV[cur ^ 1], w, lane, L15, quad);

        short8 qa8[2][2];
        qproj_reg(qx[0], wf, h, qa8[0], lane);
        qproj_reg(qx[1], wf, h, qa8[1], lane);

        f32x4 oT[2][4]; float ls[2] = {0.f, 0.f};
        #pragma unroll
        for (int su = 0; su < 2; ++su)
            #pragma unroll
            for (int n = 0; n < 4; ++n) { oT[su][n][0]=0.f; oT[su][n][1]=0.f; oT[su][n][2]=0.f; oT[su][n][3]=0.f; }
        attn_pass2(sK[cur], sV[cur], qa8, oT, ls, L15, quad);
        epilogue(wf, h, ls[0], oT[0], y[0], lane);
        epilogue(wf, h, ls[1], oT[1], y[1], lane);

        __syncthreads();   // attn(h) readers done + proj(h+1) writers done
    }

    store_tile(out, xbase, 2 * w + 0, y[0], L15, quad);   // tile 19 rows >=300: no store
    store_tile(out, xbase, 2 * w + 1, y[1], L15, quad);
}

// ================= Fallback (proven R2 kernel) for tiny ws =================
#define TPAD 320
#define KSTR 72
#define VSTR 328
#define WSTR 72
#define NWAVE 8
#define MAXTILE 3

__global__ __launch_bounds__(512, 1)
void mha_mfma(const float* __restrict__ q, const float* __restrict__ k,
              const float* __restrict__ v,
              const float* __restrict__ Wq, const float* __restrict__ Wk,
              const float* __restrict__ Wv, const float* __restrict__ Wo,
              float* __restrict__ out)
{
    __shared__ short sK [TPAD * KSTR];
    __shared__ short sVT[DKV * VSTR];
    __shared__ short sWq[DKV * WSTR];
    __shared__ short sWk[DKV * WSTR];
    __shared__ short sWv[DKV * WSTR];
    __shared__ short sWo[DKV * WSTR];
    __shared__ short sScrF[NWAVE][16 * KSTR];

    const int tid  = threadIdx.x;
    const int w    = tid >> 6;
    const int lane = tid & 63;
    const int L15  = lane & 15;
    const int quad = lane >> 4;

    const int blk = blockIdx.x;
    const int j = blk % NJ;
    const int b = blk / NJ;
    const long xbase = ((long)b * SS + (long)j * TT) * HH;

    for (int idx = tid; idx < 20 * KSTR; idx += 512) sK[300 * KSTR + idx] = 0;
    for (int idx = tid; idx < DKV * 32; idx += 512) {
        const int d = idx >> 5, c = 300 + (idx & 31);
        if (c < VSTR) sVT[d * VSTR + c] = 0;
    }

    int myT[MAXTILE]; int nMy = 0;
    for (int t = w; t < NQT; t += NWAVE) myT[nMy++] = t;

    f32x4 y[MAXTILE][4];
    #pragma unroll
    for (int a = 0; a < MAXTILE; ++a)
        #pragma unroll
        for (int n = 0; n < 4; ++n) { y[a][n][0]=0.f; y[a][n][1]=0.f; y[a][n][2]=0.f; y[a][n][3]=0.f; }

    for (int h = 0; h < NHEAD; ++h) {
        __syncthreads();
        for (int idx = tid; idx < 4096; idx += 512) {
            const int d = idx & 63;
            const int i = idx >> 6;
            sWq[d * WSTR + i] = f2bf(Wq[i * HDW + h * DKV + d]);
            sWk[d * WSTR + i] = f2bf(Wk[i * HDW + h * DKV + d]);
            sWv[d * WSTR + i] = f2bf(Wv[i * HDW + h * DKV + d]);
            sWo[d * WSTR + i] = f2bf(Wo[(h * DKV + i) * HH + d]);
        }
        __syncthreads();

        for (int jb = w; jb < 2 * NQT; jb += NWAVE) {
            const int   isV  = jb >= NQT;
            const int   tile = isV ? jb - NQT : jb;
            const float* X   = isV ? v : k;
            const short* sW  = isV ? sWv : sWk;
            int r = tile * 16 + L15; if (r > TT - 1) r = TT - 1;
            short8 afr[2];
            #pragma unroll
            for (int kt = 0; kt < 2; ++kt) {
                const float* px = X + xbase + (long)r * HH + kt * 32 + quad * 8;
                const float4 x0 = *(const float4*)px;
                const float4 x1 = *(const float4*)(px + 4);
                short8 a;
                a[0]=f2bf(x0.x); a[1]=f2bf(x0.y); a[2]=f2bf(x0.z); a[3]=f2bf(x0.w);
                a[4]=f2bf(x1.x); a[5]=f2bf(x1.y); a[6]=f2bf(x1.z); a[7]=f2bf(x1.w);
                afr[kt] = a;
            }
            #pragma unroll
            for (int nt = 0; nt < 4; ++nt) {
                f32x4 c; c[0]=0.f; c[1]=0.f; c[2]=0.f; c[3]=0.f;
                #pragma unroll
                for (int kt = 0; kt < 2; ++kt) {
                    const short8 bfr = *(const short8*)&sW[(nt*16 + L15) * WSTR + kt*32 + quad*8];
                    c = MFMA32(afr[kt], bfr, c);
                }
                #pragma unroll
                for (int rr = 0; rr < 4; ++rr) {
                    const int s = tile*16 + quad*4 + rr;
                    if (s < TT) {
                        const short bv = f2bf(c[rr]);
                        const int d = nt*16 + L15;
                        if (isV) sVT[d * VSTR + s] = bv;
                        else     sK [s * KSTR + d] = bv;
                    }
                }
            }
        }
        __syncthreads();

        for (int ti = 0; ti < nMy; ++ti) {
            const int tile = myT[ti];
            short8 qa[2];
            {
                int r = tile * 16 + L15; if (r > TT - 1) r = TT - 1;
                short8 afr[2];
                #pragma unroll
                for (int kt = 0; kt < 2; ++kt) {
                    const float* px = q + xbase + (long)r * HH + kt * 32 + quad * 8;
                    const float4 x0 = *(const float4*)px;
                    const float4 x1 = *(const float4*)(px + 4);
                    short8 a;
                    a[0]=f2bf(x0.x); a[1]=f2bf(x0.y); a[2]=f2bf(x0.z); a[3]=f2bf(x0.w);
                    a[4]=f2bf(x1.x); a[5]=f2bf(x1.y); a[6]=f2bf(x1.z); a[7]=f2bf(x1.w);
                    afr[kt] = a;
                }
                #pragma unroll
                for (int nt = 0; nt < 4; ++nt) {
                    f32x4 c; c[0]=0.f; c[1]=0.f; c[2]=0.f; c[3]=0.f;
                    #pragma unroll
                    for (int kt = 0; kt < 2; ++kt) {
                        const short8 bfr = *(const short8*)&sWq[(nt*16 + L15) * WSTR + kt*32 + quad*8];
                        c = MFMA32(afr[kt], bfr, c);
                    }
                    #pragma unroll
                    for (int rr = 0; rr < 4; ++rr)
                        sScrF[w][(quad*4+rr)*KSTR + nt*16 + L15] = f2bf(c[rr] * 0.125f);
                }
                LGKM_BAR();
                qa[0] = *(const short8*)&sScrF[w][L15*KSTR + quad*8];
                qa[1] = *(const short8*)&sScrF[w][L15*KSTR + 32 + quad*8];
            }

            float m[4] = {-3e38f, -3e38f, -3e38f, -3e38f};
            float l[4] = {0.f, 0.f, 0.f, 0.f};
            f32x4 o[4];
            #pragma unroll
            for (int nt = 0; nt < 4; ++nt) { o[nt][0]=0.f; o[nt][1]=0.f; o[nt][2]=0.f; o[nt][3]=0.f; }

            for (int st = 0; st < NST; ++st) {
                f32x4 s0, s1;
                s0[0]=0.f;s0[1]=0.f;s0[2]=0.f;s0[3]=0.f;
                s1[0]=0.f;s1[1]=0.f;s1[2]=0.f;s1[3]=0.f;
                #pragma unroll
                for (int kt = 0; kt < 2; ++kt) {
                    const short8 b0 = *(const short8*)&sK[(st*32      + L15) * KSTR + kt*32 + quad*8];
                    const short8 b1 = *(const short8*)&sK[(st*32 + 16 + L15) * KSTR + kt*32 + quad*8];
                    s0 = MFMA32(qa[kt], b0, s0);
                    s1 = MFMA32(qa[kt], b1, s1);
                }
                if (st == NST - 1) {
                    if (L15 >= 12) { s0[0]=-1e38f; s0[1]=-1e38f; s0[2]=-1e38f; s0[3]=-1e38f; }
                    s1[0]=-1e38f; s1[1]=-1e38f; s1[2]=-1e38f; s1[3]=-1e38f;
                }
                float corr[4];
                #pragma unroll
                for (int rr = 0; rr < 4; ++rr) {
                    float t = fmaxf(s0[rr], s1[rr]);
                    t = fmaxf(t, __shfl_xor(t, 1));
                    t = fmaxf(t, __shfl_xor(t, 2));
                    t = fmaxf(t, __shfl_xor(t, 4));
                    t = fmaxf(t, __shfl_xor(t, 8));
                    const float mn = fmaxf(m[rr], t);
                    corr[rr] = __expf(m[rr] - mn);
                    m[rr] = mn;
                    const float p0 = __expf(s0[rr] - mn);
                    const float p1 = __expf(s1[rr] - mn);
                    float rs = p0 + p1;
                    rs += __shfl_xor(rs, 1);
                    rs += __shfl_xor(rs, 2);
                    rs += __shfl_xor(rs, 4);
                    rs += __shfl_xor(rs, 8);
                    l[rr] = l[rr] * corr[rr] + rs;
                    sScrF[w][(quad*4+rr)*KSTR + L15]      = f2bf(p0);
                    sScrF[w][(quad*4+rr)*KSTR + 16 + L15] = f2bf(p1);
                }
                #pragma unroll
                for (int nt = 0; nt < 4; ++nt) {
                    o[nt][0] *= corr[0]; o[nt][1] *= corr[1];
                    o[nt][2] *= corr[2]; o[nt][3] *= corr[3];
                }
                LGKM_BAR();
                const short8 pa = *(const short8*)&sScrF[w][L15*KSTR + quad*8];
                #pragma unroll
                for (int nt = 0; nt < 4; ++nt) {
                    const short8 vb = *(const short8*)&sVT[(nt*16 + L15) * VSTR + st*32 + quad*8];
                    o[nt] = MFMA32(pa, vb, o[nt]);
                }
            }

            float linv[4];
            #pragma unroll
            for (int rr = 0; rr < 4; ++rr) linv[rr] = 1.f / l[rr];
            #pragma unroll
            for (int nt = 0; nt < 4; ++nt)
                #pragma unroll
                for (int rr = 0; rr < 4; ++rr)
                    sScrF[w][(quad*4+rr)*KSTR + nt*16 + L15] = f2bf(o[nt][rr] * linv[rr]);
            LGKM_BAR();
            const short8 oa0 = *(const short8*)&sScrF[w][L15*KSTR + quad*8];
            const short8 oa1 = *(const short8*)&sScrF[w][L15*KSTR + 32 + quad*8];
            #pragma unroll
            for (int nt = 0; nt < 4; ++nt) {
                const short8 w0 = *(const short8*)&sWo[(nt*16 + L15) * WSTR + quad*8];
                const short8 w1 = *(const short8*)&sWo[(nt*16 + L15) * WSTR + 32 + quad*8];
                y[ti][nt] = MFMA32(oa0, w0, y[ti][nt]);
                y[ti][nt] = MFMA32(oa1, w1, y[ti][nt]);
            }
        }
    }

    for (int ti = 0; ti < nMy; ++ti) {
        const int tile = myT[ti];
        #pragma unroll
        for (int nt = 0; nt < 4; ++nt)
            #pragma unroll
            for (int rr = 0; rr < 4; ++rr) {
                const int row = tile*16 + quad*4 + rr;
                if (row < TT)
                    out[xbase + (long)row * HH + nt*16 + L15] = y[ti][nt][rr];
            }
    }
}

extern "C" void kernel_launch(void* const* d_in, const int* in_sizes, int n_in,
                              void* d_out, int out_size, void* d_ws, size_t ws_size,
                              hipStream_t stream) {
    const float* q  = (const float*)d_in[0];
    const float* k  = (const float*)d_in[1];
    const float* v  = (const float*)d_in[2];
    const float* Wq = (const float*)d_in[3];
    const float* Wk = (const float*)d_in[4];
    const float* Wv = (const float*)d_in[5];
    const float* Wo = (const float*)d_in[6];
    float* out = (float*)d_out;

    if (ws_size >= WS_BYTES) {
        unsigned short* ws = (unsigned short*)d_ws;
        wfrag_kernel<<<160, 64, 0, stream>>>(Wq, Wk, Wv, Wo, ws);
        attn8<<<NB * NJ, 640, 0, stream>>>(q, k, v, ws, out);
    } else {
        mha_mfma<<<NB * NJ, 512, 0, stream>>>(q, k, v, Wq, Wk, Wv, Wo, out);
    }
}